// Round 8
// baseline (662.856 us; speedup 1.0000x reference)
//
#include <hip/hip_runtime.h>
#include <cstdint>
#include <cstddef>

// Problem constants (B=16, T=1024, D=256, K=1024)
namespace {
constexpr int NROW = 16384;   // B*T
constexpr int KC   = 1024;    // codes
constexpr int DIM  = 256;
constexpr int MT   = 128;     // rows per block (argmin GEMM)
constexpr int KSPLIT = 8;     // codes partitioned across blocks
constexpr int KPB  = KC / KSPLIT;   // 128 codes per block
constexpr int FCAP = 8192;    // flagged-row capacity (expect ~450)
constexpr int RPB  = 4;       // flagged rows per recheck block
}

typedef __attribute__((ext_vector_type(8))) short bf16x8;
typedef __attribute__((ext_vector_type(4))) float f32x4;
typedef unsigned long long u64;
typedef uint32_t u32;

// Monotone float -> uint key (ascending), for packed argmin with index tie-break.
__device__ __forceinline__ unsigned fkey(float s) {
  unsigned u = __float_as_uint(s);
  return ((int)u >= 0) ? (u ^ 0x80000000u) : ~u;
}
__device__ __forceinline__ float unfkey(unsigned u) {
  return __uint_as_float((u & 0x80000000u) ? (u ^ 0x80000000u) : ~u);
}

// Split fp32 a into RNE-bf16 hi + RNE-bf16 of exact residual (low 16 bits each).
__device__ __forceinline__ void split2(float a, u32& h, u32& l) {
  const u32 u  = __float_as_uint(a);
  const u32 rh = (u + 0x7fffu + ((u >> 16) & 1u)) >> 16;
  const float ah = __uint_as_float(rh << 16);
  const float al = a - ah;                      // exact (Sterbenz)
  const u32 v  = __float_as_uint(al);
  const u32 rl = (v + 0x7fffu + ((v >> 16) & 1u)) >> 16;
  h = rh & 0xffffu; l = rl & 0xffffu;
}

// numpy pairwise sum of squares of 256 floats, bit-exact emulation.
__device__ __forceinline__ float np_sumsq_256(const float* __restrict__ p) {
  float half[2];
  #pragma unroll
  for (int h = 0; h < 2; h++) {
    const float* q = p + h * 128;
    float r[8];
    #pragma unroll
    for (int j = 0; j < 8; j++) r[j] = __fmul_rn(q[j], q[j]);
    #pragma unroll 1
    for (int i = 8; i < 128; i += 8)
      #pragma unroll
      for (int j = 0; j < 8; j++)
        r[j] = __fadd_rn(r[j], __fmul_rn(q[i + j], q[i + j]));
    half[h] = __fadd_rn(__fadd_rn(__fadd_rn(r[0], r[1]), __fadd_rn(r[2], r[3])),
                        __fadd_rn(__fadd_rn(r[4], r[5]), __fadd_rn(r[6], r[7])));
  }
  return __fadd_rn(half[0], half[1]);
}

// ------------------------------------------------- pack planes + wnorm ----
__global__ __launch_bounds__(256)
void pack_wnorm_kernel(const float4* __restrict__ x4, const float4* __restrict__ w4,
                       const float* __restrict__ w,
                       uint4* __restrict__ xh4, uint4* __restrict__ xl4,
                       uint4* __restrict__ wh4, uint4* __restrict__ wl4,
                       float* __restrict__ wnorm) {
  if (blockIdx.x >= 2176) {
    const int k = (blockIdx.x - 2176) * 256 + threadIdx.x;
    wnorm[k] = np_sumsq_256(&w[k * DIM]);
    return;
  }
  const int g = blockIdx.x * 256 + threadIdx.x;
  const float4* src; uint4* dh; uint4* dl; int gg;
  if (g < 524288) { gg = g;          src = x4; dh = xh4; dl = xl4; }
  else            { gg = g - 524288; src = w4; dh = wh4; dl = wl4; }
  const float4 a = src[gg * 2], b = src[gg * 2 + 1];
  u32 h[8], l[8];
  split2(a.x, h[0], l[0]); split2(a.y, h[1], l[1]);
  split2(a.z, h[2], l[2]); split2(a.w, h[3], l[3]);
  split2(b.x, h[4], l[4]); split2(b.y, h[5], l[5]);
  split2(b.z, h[6], l[6]); split2(b.w, h[7], l[7]);
  uint4 H, L;
  H.x = h[0] | (h[1] << 16); H.y = h[2] | (h[3] << 16);
  H.z = h[4] | (h[5] << 16); H.w = h[6] | (h[7] << 16);
  L.x = l[0] | (l[1] << 16); L.y = l[2] | (l[3] << 16);
  L.z = l[4] | (l[5] << 16); L.w = l[6] | (l[7] << 16);
  dh[gg] = H; dl[gg] = L;
}

// ------------------------------------------- split-bf16 MFMA dist + top-2 ----
// R3/R16 structure (best measured): single 32 KB buffer, __syncthreads
// staging, 4 blocks/CU, XOR bank swizzle (rule #21: pre-swizzled global
// source + swizzled ds_read, LDS dest linear). R13 (dbuf) / R14 (counted
// vmcnt) measured null; R15 (atomic dw) regressed — all reverted.
__global__ __launch_bounds__(256, 4)
void dist_mfma_kernel(const ushort* __restrict__ xh, const ushort* __restrict__ xl,
                      const ushort* __restrict__ wh, const ushort* __restrict__ wl,
                      const float* __restrict__ wnorm,
                      u64* __restrict__ pairs) {
  __shared__ __align__(16) u32 lds[8192];   // 32 KB: AH 8K | AL 8K | BH 8K | BL 8K

  const int tid  = threadIdx.x;
  const int lane = tid & 63;
  const int wv   = tid >> 6;
  const int quad = lane >> 4;
  const int idx16 = lane & 15;
  const int bid  = blockIdx.x;
  const int rowBase = (((bid >> 6) << 3) | (bid & 7)) * MT;
  const int sp      = (bid >> 3) & 7;
  const int kbase   = sp * KPB;

  // 32 staging chunks of 1 KB (16 rows x 64 B); wave wv handles 8.
  // Source slot is pre-swizzled: LDS(row, s) holds global(row, s ^ ((row>>1)&3)).
  const int subrow = lane >> 2, grp = lane & 3;
  const int sgrp = grp ^ ((subrow >> 1) & 3);
  const ushort* gptr[8];
  u32 ldst[8];
  #pragma unroll
  for (int j = 0; j < 8; j++) {
    const int c = wv * 8 + j;
    const ushort* plane; int r0; u32 dstB;
    if (c < 8)       { plane = xh + rowBase * DIM; r0 = c * 16;        dstB = c * 1024; }
    else if (c < 16) { plane = xl + rowBase * DIM; r0 = (c - 8) * 16;  dstB = 8192 + (c - 8) * 1024; }
    else if (c < 24) { plane = wh + kbase * DIM;   r0 = (c - 16) * 16; dstB = 16384 + (c - 16) * 1024; }
    else             { plane = wl + kbase * DIM;   r0 = (c - 24) * 16; dstB = 24576 + (c - 24) * 1024; }
    gptr[j] = plane + (r0 + subrow) * DIM + sgrp * 8;
    ldst[j] = dstB >> 2;
  }

  f32x4 acc[2][8];
  #pragma unroll
  for (int rt = 0; rt < 2; rt++)
    #pragma unroll
    for (int ct = 0; ct < 8; ct++) acc[rt][ct] = (f32x4){0.f, 0.f, 0.f, 0.f};

  // Read-side swizzle: both ar and br are ≡ idx16 (mod 16), so the XOR term
  // is uniform per lane across all A/B fragment reads.
  const int slotOff = (quad ^ ((idx16 >> 1) & 3)) * 16;

  #pragma unroll 1
  for (int kc = 0; kc < DIM / 32; kc++) {
    __syncthreads();   // previous readers done
    #pragma unroll
    for (int j = 0; j < 8; j++) {
      __builtin_amdgcn_global_load_lds(
          (const __attribute__((address_space(1))) u32*)(gptr[j]),
          (__attribute__((address_space(3))) u32*)&lds[ldst[j]], 16, 0, 0);
      gptr[j] += 32;   // next 32 K-elems
    }
    __syncthreads();   // drains vmcnt; LDS visible

    bf16x8 Ah[2], Al[2];
    #pragma unroll
    for (int rt = 0; rt < 2; rt++) {
      const int ar = wv * 32 + rt * 16 + idx16;
      Ah[rt] = *(const bf16x8*)((const char*)lds + ar * 64 + slotOff);
      Al[rt] = *(const bf16x8*)((const char*)lds + 8192 + ar * 64 + slotOff);
    }
    #pragma unroll
    for (int ct = 0; ct < 8; ct++) {
      const int br = ct * 16 + idx16;
      const bf16x8 Bh = *(const bf16x8*)((const char*)lds + 16384 + br * 64 + slotOff);
      const bf16x8 Bl = *(const bf16x8*)((const char*)lds + 24576 + br * 64 + slotOff);
      #pragma unroll
      for (int rt = 0; rt < 2; rt++) {
        acc[rt][ct] = __builtin_amdgcn_mfma_f32_16x16x32_bf16(Al[rt], Bh, acc[rt][ct], 0, 0, 0);
        acc[rt][ct] = __builtin_amdgcn_mfma_f32_16x16x32_bf16(Ah[rt], Bl, acc[rt][ct], 0, 0, 0);
        acc[rt][ct] = __builtin_amdgcn_mfma_f32_16x16x32_bf16(Ah[rt], Bh, acc[rt][ct], 0, 0, 0);
      }
    }
  }

  // Epilogue: score = wnorm - 2*dot; per-lane top-2, then 4-stage butterfly.
  u64 b0[2][4], b1[2][4];
  #pragma unroll
  for (int rt = 0; rt < 2; rt++)
    #pragma unroll
    for (int reg = 0; reg < 4; reg++) { b0[rt][reg] = ~0ULL; b1[rt][reg] = ~0ULL; }

  #pragma unroll
  for (int ct = 0; ct < 8; ct++) {
    const int col = kbase + ct * 16 + idx16;
    const float wn = wnorm[col];
    #pragma unroll
    for (int rt = 0; rt < 2; rt++) {
      #pragma unroll
      for (int reg = 0; reg < 4; reg++) {
        const float s = fmaf(-2.0f, acc[rt][ct][reg], wn);
        const u64 p = ((u64)fkey(s) << 32) | (unsigned)col;
        if (p < b1[rt][reg]) {
          if (p < b0[rt][reg]) { b1[rt][reg] = b0[rt][reg]; b0[rt][reg] = p; }
          else                 { b1[rt][reg] = p; }
        }
      }
    }
  }

  #pragma unroll
  for (int m = 1; m <= 8; m <<= 1) {
    #pragma unroll
    for (int rt = 0; rt < 2; rt++) {
      #pragma unroll
      for (int reg = 0; reg < 4; reg++) {
        const u64 o0 = __shfl_xor(b0[rt][reg], m);
        const u64 o1 = __shfl_xor(b1[rt][reg], m);
        if (o0 < b0[rt][reg]) {
          b1[rt][reg] = (b0[rt][reg] < o1) ? b0[rt][reg] : o1;
          b0[rt][reg] = o0;
        } else {
          b1[rt][reg] = (b1[rt][reg] < o0) ? b1[rt][reg] : o0;
        }
      }
    }
  }

  if (idx16 == 0) {
    #pragma unroll
    for (int rt = 0; rt < 2; rt++) {
      #pragma unroll
      for (int reg = 0; reg < 4; reg++) {
        const int row = rowBase + wv * 32 + rt * 16 + quad * 4 + reg;
        pairs[row * 16 + sp * 2 + 0] = b0[rt][reg];
        pairs[row * 16 + sp * 2 + 1] = b1[rt][reg];
      }
    }
  }
}

// ------------------------------------- merge splits + flag + counts ----
__global__ __launch_bounds__(256)
void merge_kernel(const u64* __restrict__ pairs,
                  int* __restrict__ idx, float* __restrict__ counts,
                  int* __restrict__ flags, int* __restrict__ counter) {
  const int row = blockIdx.x * 256 + threadIdx.x;
  const u64* p = &pairs[row * 16];
  u64 B0 = p[0], B1 = p[1];
  #pragma unroll
  for (int s = 1; s < KSPLIT; s++) {
    const u64 c0 = p[s * 2], c1 = p[s * 2 + 1];
    if (c0 < B0) { B1 = (B0 < c1) ? B0 : c1; B0 = c0; }
    else         { B1 = (B1 < c0) ? B1 : c0; }
  }
  const int k = (int)(B0 & 0xffffffffULL);
  idx[row] = k;
  atomicAdd(&counts[k], 1.0f);
  const float s0 = unfkey((unsigned)(B0 >> 32));
  const float s1 = unfkey((unsigned)(B1 >> 32));
  if (s1 - s0 < 2e-4f) {
    const int pos = atomicAdd(counter, 1);
    if (pos < FCAP) flags[pos] = row;
  }
}

// --------------------- np-fp32-emulating recheck; adjusts counts on flips ----
// R11: 1024 threads/block, one code per thread; x rows pre-converted to
// double in LDS once; u64 argmin via wave shfl_xor reduce. FMA order per
// (row,code) unchanged -> bit-identical results.
// R16: prefix_cs FUSED via last-block-done pattern — every block
// __threadfence + atomicAdd(done); the block seeing prev==gridDim-1 runs the
// exact former prefix_cs body (cs + starts/cursor scan) with its 1024
// threads. Saves one launch + gap. Main body wrapped in a block-uniform
// guard so ALL blocks reach the done-increment.
__global__ __launch_bounds__(1024)
void recheck_np_kernel(const float* __restrict__ x, const float* __restrict__ w,
                       const float* __restrict__ wnorm,
                       const int* __restrict__ flags, const int* __restrict__ counter,
                       int* __restrict__ idx, float* __restrict__ counts,
                       const float* __restrict__ ema_cs,
                       float* __restrict__ out_cs, float* __restrict__ cs_ws,
                       int* __restrict__ starts, int* __restrict__ cursor,
                       int* __restrict__ done) {
  __shared__ float  xs[RPB][DIM];    // 4 KB
  __shared__ double xd[RPB][DIM];    // 8 KB
  __shared__ float  x2sh[RPB];
  __shared__ u64    red[RPB][16];
  __shared__ int    scl[1024];       // 4 KB (tail scan)
  __shared__ float  pl[17];
  __shared__ int    lastFlag;

  const int cnt  = min(*counter, FCAP);
  const int base = blockIdx.x * RPB;

  if (base < cnt) {                  // block-uniform guard
    const int nr = min(RPB, cnt - base);

    {
      const int r = threadIdx.x >> 8, d = threadIdx.x & 255;
      const float v = (r < nr) ? x[flags[base + r] * DIM + d] : 0.0f;
      xs[r][d] = v;
      xd[r][d] = (double)v;
    }
    __syncthreads();
    if (threadIdx.x < RPB) x2sh[threadIdx.x] = np_sumsq_256(xs[threadIdx.x]);
    __syncthreads();

    double x2d[RPB];
    #pragma unroll
    for (int r = 0; r < RPB; r++) x2d[r] = (double)x2sh[r];

    const int k = threadIdx.x;                    // one code per thread
    const float* __restrict__ wr = &w[k * DIM];
    const double w2 = (double)wnorm[k];

    double dot[RPB];
    #pragma unroll
    for (int r = 0; r < RPB; r++) dot[r] = 0.0;

    float4 wv[4];
    #pragma unroll
    for (int q = 0; q < 4; q++) wv[q] = *(const float4*)&wr[q * 4];

    #pragma unroll 1
    for (int d = 0; d < DIM; d += 16) {
      float4 cur[4];
      #pragma unroll
      for (int q = 0; q < 4; q++) cur[q] = wv[q];
      if (d + 16 < DIM) {
        #pragma unroll
        for (int q = 0; q < 4; q++) wv[q] = *(const float4*)&wr[d + 16 + q * 4];
      }
      #pragma unroll
      for (int q = 0; q < 4; q++) {
        const double wa = (double)cur[q].x, wb = (double)cur[q].y,
                     wc = (double)cur[q].z, wd_ = (double)cur[q].w;
        #pragma unroll
        for (int r = 0; r < RPB; r++) {
          dot[r] = fma(xd[r][d + q * 4 + 0], wa,  dot[r]);
          dot[r] = fma(xd[r][d + q * 4 + 1], wb,  dot[r]);
          dot[r] = fma(xd[r][d + q * 4 + 2], wc,  dot[r]);
          dot[r] = fma(xd[r][d + q * 4 + 3], wd_, dot[r]);
        }
      }
    }

    u64 key[RPB];
    #pragma unroll
    for (int r = 0; r < RPB; r++) {
      const float mmf = (float)dot[r];
      const float S1  = (float)(x2d[r] + w2);
      const float D   = (float)((double)S1 - 2.0 * (double)mmf);
      key[r] = ((u64)fkey(D) << 32) | (unsigned)k;
    }

    // wave-level u64 min (6 butterfly stages)
    #pragma unroll
    for (int m = 1; m < 64; m <<= 1) {
      #pragma unroll
      for (int r = 0; r < RPB; r++) {
        const u64 o = __shfl_xor(key[r], m);
        if (o < key[r]) key[r] = o;
      }
    }
    if ((threadIdx.x & 63) == 0) {
      const int wid = threadIdx.x >> 6;
      #pragma unroll
      for (int r = 0; r < RPB; r++) red[r][wid] = key[r];
    }
    __syncthreads();
    if (threadIdx.x < 64) {                       // wave 0: 16 lanes per row
      const int r = threadIdx.x >> 4, l = threadIdx.x & 15;
      u64 kk = red[r][l];
      #pragma unroll
      for (int m = 1; m < 16; m <<= 1) {
        const u64 o = __shfl_xor(kk, m);
        if (o < kk) kk = o;
      }
      if (l == 0 && r < nr) {
        const int row  = flags[base + r];
        const int newk = (int)(kk & 0xffffffffULL);
        const int oldk = idx[row];
        if (newk != oldk) {
          idx[row] = newk;
          atomicAdd(&counts[newk],  1.0f);
          atomicAdd(&counts[oldk], -1.0f);
        }
      }
    }
  }

  // ---- R16 tail: last-block-done -> fused cs + starts/cursor scan ----
  __threadfence();                    // counts flips visible device-wide
  __syncthreads();
  if (threadIdx.x == 0)
    lastFlag = (atomicAdd(done, 1) == (int)gridDim.x - 1);
  __syncthreads();
  if (!lastFlag) return;
  __threadfence();                    // acquire side

  {
    const int t = threadIdx.x;
    const int ci = (int)counts[t];
    scl[t] = ci;
    const float c = ema_cs[t] * 0.99f + 0.01f * counts[t];
    float v = c;
    #pragma unroll
    for (int off = 32; off > 0; off >>= 1) v += __shfl_down(v, off);
    if ((t & 63) == 0) pl[t >> 6] = v;
    __syncthreads();
    if (t == 0) {
      float n = 0.0f;
      for (int i = 0; i < 16; i++) n += pl[i];
      pl[16] = n;
    }
    __syncthreads();
    const float n = pl[16];
    const float csv = (c + 1e-5f) / (n + 1024.0f * 1e-5f) * n;
    out_cs[t] = csv;
    cs_ws[t]  = csv;
    #pragma unroll
    for (int off = 1; off < 1024; off <<= 1) {
      const int add = (t >= off) ? scl[t - off] : 0;
      __syncthreads();
      scl[t] += add;
      __syncthreads();
    }
    const int excl = scl[t] - ci;
    starts[t] = excl;
    cursor[t] = excl;
  }
}

// ------------------------------------------------------ bucket scatter ----
__global__ __launch_bounds__(256)
void scatter_kernel(const int* __restrict__ idx, int* __restrict__ cursor,
                    int* __restrict__ bucket) {
  const int row = blockIdx.x * 256 + threadIdx.x;
  const int k = idx[row];
  const int pos = atomicAdd(&cursor[k], 1);
  bucket[pos] = row;
}

// ----------------------------------- per-cluster dw reduction (no atomics) ----
__global__ __launch_bounds__(256)
void dw_bucket_kernel(const float4* __restrict__ x4, const int* __restrict__ bucket,
                      const int* __restrict__ starts, const float* __restrict__ counts,
                      float4* __restrict__ dw4) {
  __shared__ float4 red[4][64];
  const int k   = blockIdx.x;
  const int d4  = threadIdx.x & 63;
  const int rg  = threadIdx.x >> 6;
  const int s   = starts[k];
  const int e   = s + (int)counts[k];
  float4 acc = {0.f, 0.f, 0.f, 0.f};
  for (int i = s + rg; i < e; i += 4) {
    const float4 v = x4[bucket[i] * 64 + d4];
    acc.x += v.x; acc.y += v.y; acc.z += v.z; acc.w += v.w;
  }
  red[rg][d4] = acc;
  __syncthreads();
  if (rg == 0) {
    const float4 a1 = red[1][d4], a2 = red[2][d4], a3 = red[3][d4];
    acc.x += a1.x + a2.x + a3.x;
    acc.y += a1.y + a2.y + a3.y;
    acc.z += a1.z + a2.z + a3.z;
    acc.w += a1.w + a2.w + a3.w;
    dw4[k * 64 + d4] = acc;
  }
}

// ------------------------------------------- quantize + loss (no atomics) ----
__global__ __launch_bounds__(256)
void quant_loss_kernel(const float4* __restrict__ x4,
                       const float4* __restrict__ w4,
                       const int* __restrict__ idx,
                       float4* __restrict__ outq,
                       float* __restrict__ partials) {
  __shared__ float lds[4];
  const int g  = blockIdx.x * 256 + threadIdx.x;
  const int n  = g >> 6;
  const int d4 = g & 63;
  const float4 xv = x4[g];
  const int   k  = idx[n];
  const float4 qv = w4[k * 64 + d4];
  float4 r;
  r.x = xv.x + (qv.x - xv.x);
  r.y = xv.y + (qv.y - xv.y);
  r.z = xv.z + (qv.z - xv.z);
  r.w = xv.w + (qv.w - xv.w);
  outq[g] = r;

  const float dx = xv.x - r.x, dy = xv.y - r.y, dz = xv.z - r.z, dwv = xv.w - r.w;
  float s = dx * dx + dy * dy + dz * dz + dwv * dwv;
  #pragma unroll
  for (int off = 32; off > 0; off >>= 1) s += __shfl_down(s, off);
  if ((threadIdx.x & 63) == 0) lds[threadIdx.x >> 6] = s;
  __syncthreads();
  if (threadIdx.x == 0) partials[blockIdx.x] = lds[0] + lds[1] + lds[2] + lds[3];
}

// --------------------------------- fused ema_w/embed (+ loss finalize) ----
__global__ __launch_bounds__(256)
void emb_loss_kernel(const float* __restrict__ ema_w, const float* __restrict__ dw,
                     const float* __restrict__ cs, const float* __restrict__ partials,
                     float* __restrict__ out_ema_w, float* __restrict__ out_embed,
                     float* __restrict__ out_loss) {
  if (blockIdx.x == 1024) {
    __shared__ float lds[4];
    float s = 0.0f;
    for (int i = threadIdx.x; i < 4096; i += 256) s += partials[i];
    #pragma unroll
    for (int off = 32; off > 0; off >>= 1) s += __shfl_down(s, off);
    if ((threadIdx.x & 63) == 0) lds[threadIdx.x >> 6] = s;
    __syncthreads();
    if (threadIdx.x == 0) {
      const float total = lds[0] + lds[1] + lds[2] + lds[3];
      out_loss[0] = 0.25f * (total / 4194304.0f);
    }
    return;
  }
  const int g = blockIdx.x * 256 + threadIdx.x;
  const int k = g >> 8;
  const float e = ema_w[g] * 0.99f + 0.01f * dw[g];
  out_ema_w[g] = e;
  out_embed[g] = e / cs[k];
}

// ------------------------------------------------------------------ launch ----
extern "C" void kernel_launch(void* const* d_in, const int* in_sizes, int n_in,
                              void* d_out, int out_size, void* d_ws, size_t ws_size,
                              hipStream_t stream) {
  const float* x       = (const float*)d_in[0];
  const float* embed_w = (const float*)d_in[1];
  const float* ema_cs  = (const float*)d_in[2];
  const float* ema_w   = (const float*)d_in[3];

  float* out        = (float*)d_out;
  float* out_q      = out;                 // 4194304
  float* out_loss   = out + 4194304;       // 1
  float* out_embed  = out + 4194305;       // 262144
  float* out_cs     = out + 4456449;       // 1024
  float* out_ema_w  = out + 4457473;       // 262144

  char* ws = (char*)d_ws;
  u64*   pairs    = (u64*)  (ws + 0);           // 2 MB [0, 2097152)
  int*   bucket   = (int*)  (ws + 0);           // 64 KB  (alias, post-merge)
  float* dw       = (float*)(ws + 1048576);     // 1 MB   (alias pairs hi, post-merge)
  int*   idx      = (int*)  (ws + 2097152);     // 64 KB  [2097152, 2162688)
  float* counts   = (float*)(ws + 2162688);     // 4 KB
  int*   counter  = (int*)  (ws + 2166784);     // 4 B (adjacent to counts)
  int*   done     = (int*)  (ws + 2166788);     // 4 B (R16 last-block counter)
  int*   flags    = (int*)  (ws + 2166912);     // 32 KB
  float* wnorm    = (float*)(ws + 2199680);     // 4 KB
  float* cs_ws    = (float*)(ws + 2203776);     // 4 KB
  float* partials = (float*)(ws + 2207872);     // 16 KB
  int*   starts   = (int*)  (ws + 2224256);     // 4 KB
  int*   cursor   = (int*)  (ws + 2228352);     // 4 KB
  ushort* wh      = (ushort*)(ws + 2232448);    // 512 KB [2232448, 2756736)
  ushort* wl      = (ushort*)(ws + 2756736);    // 512 KB [2756736, 3281024)
  // ^ R8/R10 BUG: wl was at 2756608, overlapping wh's last 128 B (code 1023
  //   hi-plane clobbered by code 0 lo-plane) -> deterministic argmin flips.

  // x planes alias out_q (16 MB exactly; overwritten by quant_loss later).
  ushort* xh = (ushort*)out_q;                  // 8 MB
  ushort* xl = (ushort*)out_q + 4194304;        // 8 MB

  hipMemsetAsync(counts, 0, 4104, stream);      // counts + counter + done

  pack_wnorm_kernel<<<2180, 256, 0, stream>>>(
      (const float4*)x, (const float4*)embed_w, embed_w,
      (uint4*)xh, (uint4*)xl, (uint4*)wh, (uint4*)wl, wnorm);
  dist_mfma_kernel<<<(NROW / MT) * KSPLIT, 256, 0, stream>>>(xh, xl, wh, wl, wnorm, pairs);
  merge_kernel<<<NROW / 256, 256, 0, stream>>>(pairs, idx, counts, flags, counter);
  recheck_np_kernel<<<FCAP / RPB, 1024, 0, stream>>>(x, embed_w, wnorm, flags, counter,
                                                     idx, counts, ema_cs, out_cs, cs_ws,
                                                     starts, cursor, done);
  scatter_kernel<<<NROW / 256, 256, 0, stream>>>(idx, cursor, bucket);
  dw_bucket_kernel<<<KC, 256, 0, stream>>>((const float4*)x, bucket, starts, counts,
                                           (float4*)dw);
  quant_loss_kernel<<<NROW * 64 / 256, 256, 0, stream>>>(
      (const float4*)x, (const float4*)embed_w, idx, (float4*)out_q, partials);
  emb_loss_kernel<<<KC * DIM / 256 + 1, 256, 0, stream>>>(
      ema_w, dw, cs_ws, partials, out_ema_w, out_embed, out_loss);
}

// Round 9
// 196.622 us; speedup vs baseline: 3.3712x; 3.3712x over previous
//
#include <hip/hip_runtime.h>
#include <cstdint>
#include <cstddef>

// Problem constants (B=16, T=1024, D=256, K=1024)
namespace {
constexpr int NROW = 16384;   // B*T
constexpr int KC   = 1024;    // codes
constexpr int DIM  = 256;
constexpr int MT   = 128;     // rows per block (argmin GEMM)
constexpr int KSPLIT = 8;     // codes partitioned across blocks
constexpr int KPB  = KC / KSPLIT;   // 128 codes per block
constexpr int FCAP = 8192;    // flagged-row capacity (expect ~450)
constexpr int RPB  = 4;       // flagged rows per recheck block
}

typedef __attribute__((ext_vector_type(8))) short bf16x8;
typedef __attribute__((ext_vector_type(4))) float f32x4;
typedef unsigned long long u64;
typedef uint32_t u32;

// Monotone float -> uint key (ascending), for packed argmin with index tie-break.
__device__ __forceinline__ unsigned fkey(float s) {
  unsigned u = __float_as_uint(s);
  return ((int)u >= 0) ? (u ^ 0x80000000u) : ~u;
}
__device__ __forceinline__ float unfkey(unsigned u) {
  return __uint_as_float((u & 0x80000000u) ? (u ^ 0x80000000u) : ~u);
}

// Split fp32 a into RNE-bf16 hi + RNE-bf16 of exact residual (low 16 bits each).
__device__ __forceinline__ void split2(float a, u32& h, u32& l) {
  const u32 u  = __float_as_uint(a);
  const u32 rh = (u + 0x7fffu + ((u >> 16) & 1u)) >> 16;
  const float ah = __uint_as_float(rh << 16);
  const float al = a - ah;                      // exact (Sterbenz)
  const u32 v  = __float_as_uint(al);
  const u32 rl = (v + 0x7fffu + ((v >> 16) & 1u)) >> 16;
  h = rh & 0xffffu; l = rl & 0xffffu;
}

// numpy pairwise sum of squares of 256 floats, bit-exact emulation.
__device__ __forceinline__ float np_sumsq_256(const float* __restrict__ p) {
  float half[2];
  #pragma unroll
  for (int h = 0; h < 2; h++) {
    const float* q = p + h * 128;
    float r[8];
    #pragma unroll
    for (int j = 0; j < 8; j++) r[j] = __fmul_rn(q[j], q[j]);
    #pragma unroll 1
    for (int i = 8; i < 128; i += 8)
      #pragma unroll
      for (int j = 0; j < 8; j++)
        r[j] = __fadd_rn(r[j], __fmul_rn(q[i + j], q[i + j]));
    half[h] = __fadd_rn(__fadd_rn(__fadd_rn(r[0], r[1]), __fadd_rn(r[2], r[3])),
                        __fadd_rn(__fadd_rn(r[4], r[5]), __fadd_rn(r[6], r[7])));
  }
  return __fadd_rn(half[0], half[1]);
}

// ------------------------------------------------- pack planes + wnorm ----
__global__ __launch_bounds__(256)
void pack_wnorm_kernel(const float4* __restrict__ x4, const float4* __restrict__ w4,
                       const float* __restrict__ w,
                       uint4* __restrict__ xh4, uint4* __restrict__ xl4,
                       uint4* __restrict__ wh4, uint4* __restrict__ wl4,
                       float* __restrict__ wnorm) {
  if (blockIdx.x >= 2176) {
    const int k = (blockIdx.x - 2176) * 256 + threadIdx.x;
    wnorm[k] = np_sumsq_256(&w[k * DIM]);
    return;
  }
  const int g = blockIdx.x * 256 + threadIdx.x;
  const float4* src; uint4* dh; uint4* dl; int gg;
  if (g < 524288) { gg = g;          src = x4; dh = xh4; dl = xl4; }
  else            { gg = g - 524288; src = w4; dh = wh4; dl = wl4; }
  const float4 a = src[gg * 2], b = src[gg * 2 + 1];
  u32 h[8], l[8];
  split2(a.x, h[0], l[0]); split2(a.y, h[1], l[1]);
  split2(a.z, h[2], l[2]); split2(a.w, h[3], l[3]);
  split2(b.x, h[4], l[4]); split2(b.y, h[5], l[5]);
  split2(b.z, h[6], l[6]); split2(b.w, h[7], l[7]);
  uint4 H, L;
  H.x = h[0] | (h[1] << 16); H.y = h[2] | (h[3] << 16);
  H.z = h[4] | (h[5] << 16); H.w = h[6] | (h[7] << 16);
  L.x = l[0] | (l[1] << 16); L.y = l[2] | (l[3] << 16);
  L.z = l[4] | (l[5] << 16); L.w = l[6] | (l[7] << 16);
  dh[gg] = H; dl[gg] = L;
}

// ------------------------------------------- split-bf16 MFMA dist + top-2 ----
// KSPLIT=8: block = 128 rows x 128 codes, 32 KB LDS. Staging is the R7-verified
// lane-contiguous global_load_lds pattern. XCD swizzle: the 8 ksplit siblings
// of a row-block share bid%8 -> same XCD L2.
// R12: +XOR bank swizzle (slot ^= (row>>1)&3, rule #21: pre-swizzled global
// source + swizzled ds_read, LDS dest stays linear) kills the 8-way conflict
// on ds_read_b128. +launch_bounds(256,4): 4 blocks/CU.
// R13 (dbuf+drain), R14 (counted vmcnt) measured null; R15 (atomic dw) and
// R16 (device-fence fusion) regressed — all reverted. This is the best
// measured configuration (193.0 us total).
__global__ __launch_bounds__(256, 4)
void dist_mfma_kernel(const ushort* __restrict__ xh, const ushort* __restrict__ xl,
                      const ushort* __restrict__ wh, const ushort* __restrict__ wl,
                      const float* __restrict__ wnorm,
                      u64* __restrict__ pairs) {
  __shared__ __align__(16) u32 lds[8192];   // 32 KB: AH 8K | AL 8K | BH 8K | BL 8K

  const int tid  = threadIdx.x;
  const int lane = tid & 63;
  const int wv   = tid >> 6;
  const int quad = lane >> 4;
  const int idx16 = lane & 15;
  const int bid  = blockIdx.x;
  const int rowBase = (((bid >> 6) << 3) | (bid & 7)) * MT;
  const int sp      = (bid >> 3) & 7;
  const int kbase   = sp * KPB;

  // 32 staging chunks of 1 KB (16 rows x 64 B); wave wv handles 8.
  // Source slot is pre-swizzled: LDS(row, s) holds global(row, s ^ ((row>>1)&3)).
  const int subrow = lane >> 2, grp = lane & 3;
  const int sgrp = grp ^ ((subrow >> 1) & 3);
  const ushort* gptr[8];
  u32 ldst[8];
  #pragma unroll
  for (int j = 0; j < 8; j++) {
    const int c = wv * 8 + j;
    const ushort* plane; int r0; u32 dstB;
    if (c < 8)       { plane = xh + rowBase * DIM; r0 = c * 16;        dstB = c * 1024; }
    else if (c < 16) { plane = xl + rowBase * DIM; r0 = (c - 8) * 16;  dstB = 8192 + (c - 8) * 1024; }
    else if (c < 24) { plane = wh + kbase * DIM;   r0 = (c - 16) * 16; dstB = 16384 + (c - 16) * 1024; }
    else             { plane = wl + kbase * DIM;   r0 = (c - 24) * 16; dstB = 24576 + (c - 24) * 1024; }
    gptr[j] = plane + (r0 + subrow) * DIM + sgrp * 8;
    ldst[j] = dstB >> 2;
  }

  f32x4 acc[2][8];
  #pragma unroll
  for (int rt = 0; rt < 2; rt++)
    #pragma unroll
    for (int ct = 0; ct < 8; ct++) acc[rt][ct] = (f32x4){0.f, 0.f, 0.f, 0.f};

  // Read-side swizzle: both ar and br are ≡ idx16 (mod 16), so the XOR term
  // is uniform per lane across all A/B fragment reads.
  const int slotOff = (quad ^ ((idx16 >> 1) & 3)) * 16;

  #pragma unroll 1
  for (int kc = 0; kc < DIM / 32; kc++) {
    __syncthreads();   // previous readers done
    #pragma unroll
    for (int j = 0; j < 8; j++) {
      __builtin_amdgcn_global_load_lds(
          (const __attribute__((address_space(1))) u32*)(gptr[j]),
          (__attribute__((address_space(3))) u32*)&lds[ldst[j]], 16, 0, 0);
      gptr[j] += 32;   // next 32 K-elems
    }
    __syncthreads();   // drains vmcnt; LDS visible

    bf16x8 Ah[2], Al[2];
    #pragma unroll
    for (int rt = 0; rt < 2; rt++) {
      const int ar = wv * 32 + rt * 16 + idx16;
      Ah[rt] = *(const bf16x8*)((const char*)lds + ar * 64 + slotOff);
      Al[rt] = *(const bf16x8*)((const char*)lds + 8192 + ar * 64 + slotOff);
    }
    #pragma unroll
    for (int ct = 0; ct < 8; ct++) {
      const int br = ct * 16 + idx16;
      const bf16x8 Bh = *(const bf16x8*)((const char*)lds + 16384 + br * 64 + slotOff);
      const bf16x8 Bl = *(const bf16x8*)((const char*)lds + 24576 + br * 64 + slotOff);
      #pragma unroll
      for (int rt = 0; rt < 2; rt++) {
        acc[rt][ct] = __builtin_amdgcn_mfma_f32_16x16x32_bf16(Al[rt], Bh, acc[rt][ct], 0, 0, 0);
        acc[rt][ct] = __builtin_amdgcn_mfma_f32_16x16x32_bf16(Ah[rt], Bl, acc[rt][ct], 0, 0, 0);
        acc[rt][ct] = __builtin_amdgcn_mfma_f32_16x16x32_bf16(Ah[rt], Bh, acc[rt][ct], 0, 0, 0);
      }
    }
  }

  // Epilogue: score = wnorm - 2*dot; per-lane top-2, then 4-stage butterfly.
  u64 b0[2][4], b1[2][4];
  #pragma unroll
  for (int rt = 0; rt < 2; rt++)
    #pragma unroll
    for (int reg = 0; reg < 4; reg++) { b0[rt][reg] = ~0ULL; b1[rt][reg] = ~0ULL; }

  #pragma unroll
  for (int ct = 0; ct < 8; ct++) {
    const int col = kbase + ct * 16 + idx16;
    const float wn = wnorm[col];
    #pragma unroll
    for (int rt = 0; rt < 2; rt++) {
      #pragma unroll
      for (int reg = 0; reg < 4; reg++) {
        const float s = fmaf(-2.0f, acc[rt][ct][reg], wn);
        const u64 p = ((u64)fkey(s) << 32) | (unsigned)col;
        if (p < b1[rt][reg]) {
          if (p < b0[rt][reg]) { b1[rt][reg] = b0[rt][reg]; b0[rt][reg] = p; }
          else                 { b1[rt][reg] = p; }
        }
      }
    }
  }

  #pragma unroll
  for (int m = 1; m <= 8; m <<= 1) {
    #pragma unroll
    for (int rt = 0; rt < 2; rt++) {
      #pragma unroll
      for (int reg = 0; reg < 4; reg++) {
        const u64 o0 = __shfl_xor(b0[rt][reg], m);
        const u64 o1 = __shfl_xor(b1[rt][reg], m);
        if (o0 < b0[rt][reg]) {
          b1[rt][reg] = (b0[rt][reg] < o1) ? b0[rt][reg] : o1;
          b0[rt][reg] = o0;
        } else {
          b1[rt][reg] = (b1[rt][reg] < o0) ? b1[rt][reg] : o0;
        }
      }
    }
  }

  if (idx16 == 0) {
    #pragma unroll
    for (int rt = 0; rt < 2; rt++) {
      #pragma unroll
      for (int reg = 0; reg < 4; reg++) {
        const int row = rowBase + wv * 32 + rt * 16 + quad * 4 + reg;
        pairs[row * 16 + sp * 2 + 0] = b0[rt][reg];
        pairs[row * 16 + sp * 2 + 1] = b1[rt][reg];
      }
    }
  }
}

// ------------------------------------- merge splits + flag + counts ----
__global__ __launch_bounds__(256)
void merge_kernel(const u64* __restrict__ pairs,
                  int* __restrict__ idx, float* __restrict__ counts,
                  int* __restrict__ flags, int* __restrict__ counter) {
  const int row = blockIdx.x * 256 + threadIdx.x;
  const u64* p = &pairs[row * 16];
  u64 B0 = p[0], B1 = p[1];
  #pragma unroll
  for (int s = 1; s < KSPLIT; s++) {
    const u64 c0 = p[s * 2], c1 = p[s * 2 + 1];
    if (c0 < B0) { B1 = (B0 < c1) ? B0 : c1; B0 = c0; }
    else         { B1 = (B1 < c0) ? B1 : c0; }
  }
  const int k = (int)(B0 & 0xffffffffULL);
  idx[row] = k;
  atomicAdd(&counts[k], 1.0f);
  const float s0 = unfkey((unsigned)(B0 >> 32));
  const float s1 = unfkey((unsigned)(B1 >> 32));
  if (s1 - s0 < 2e-4f) {
    const int pos = atomicAdd(counter, 1);
    if (pos < FCAP) flags[pos] = row;
  }
}

// --------------------- np-fp32-emulating recheck; adjusts counts on flips ----
// R11 structure: 1024 threads/block, one code per thread; x rows
// pre-converted to double in LDS once; w walked in 64B lines with next-line
// prefetch; u64 argmin via wave shfl_xor reduce. FMA order per (row,code)
// unchanged -> bit-identical results. R16's device-fence fusion REVERTED:
// __threadfence() on gfx950 = per-XCD L2 writeback broadcasts; in a
// 2048-block grid it cost ~510 us (measured). Never wide device fences.
__global__ __launch_bounds__(1024)
void recheck_np_kernel(const float* __restrict__ x, const float* __restrict__ w,
                       const float* __restrict__ wnorm,
                       const int* __restrict__ flags, const int* __restrict__ counter,
                       int* __restrict__ idx, float* __restrict__ counts) {
  __shared__ float  xs[RPB][DIM];    // 4 KB
  __shared__ double xd[RPB][DIM];    // 8 KB
  __shared__ float  x2sh[RPB];
  __shared__ u64    red[RPB][16];

  const int cnt  = min(*counter, FCAP);
  const int base = blockIdx.x * RPB;
  if (base >= cnt) return;
  const int nr = min(RPB, cnt - base);

  {
    const int r = threadIdx.x >> 8, d = threadIdx.x & 255;
    const float v = (r < nr) ? x[flags[base + r] * DIM + d] : 0.0f;
    xs[r][d] = v;
    xd[r][d] = (double)v;
  }
  __syncthreads();
  if (threadIdx.x < RPB) x2sh[threadIdx.x] = np_sumsq_256(xs[threadIdx.x]);
  __syncthreads();

  double x2d[RPB];
  #pragma unroll
  for (int r = 0; r < RPB; r++) x2d[r] = (double)x2sh[r];

  const int k = threadIdx.x;                    // one code per thread
  const float* __restrict__ wr = &w[k * DIM];
  const double w2 = (double)wnorm[k];

  double dot[RPB];
  #pragma unroll
  for (int r = 0; r < RPB; r++) dot[r] = 0.0;

  float4 wv[4];
  #pragma unroll
  for (int q = 0; q < 4; q++) wv[q] = *(const float4*)&wr[q * 4];

  #pragma unroll 1
  for (int d = 0; d < DIM; d += 16) {
    float4 cur[4];
    #pragma unroll
    for (int q = 0; q < 4; q++) cur[q] = wv[q];
    if (d + 16 < DIM) {
      #pragma unroll
      for (int q = 0; q < 4; q++) wv[q] = *(const float4*)&wr[d + 16 + q * 4];
    }
    #pragma unroll
    for (int q = 0; q < 4; q++) {
      const double wa = (double)cur[q].x, wb = (double)cur[q].y,
                   wc = (double)cur[q].z, wd_ = (double)cur[q].w;
      #pragma unroll
      for (int r = 0; r < RPB; r++) {
        dot[r] = fma(xd[r][d + q * 4 + 0], wa,  dot[r]);
        dot[r] = fma(xd[r][d + q * 4 + 1], wb,  dot[r]);
        dot[r] = fma(xd[r][d + q * 4 + 2], wc,  dot[r]);
        dot[r] = fma(xd[r][d + q * 4 + 3], wd_, dot[r]);
      }
    }
  }

  u64 key[RPB];
  #pragma unroll
  for (int r = 0; r < RPB; r++) {
    const float mmf = (float)dot[r];
    const float S1  = (float)(x2d[r] + w2);
    const float D   = (float)((double)S1 - 2.0 * (double)mmf);
    key[r] = ((u64)fkey(D) << 32) | (unsigned)k;
  }

  // wave-level u64 min (6 butterfly stages)
  #pragma unroll
  for (int m = 1; m < 64; m <<= 1) {
    #pragma unroll
    for (int r = 0; r < RPB; r++) {
      const u64 o = __shfl_xor(key[r], m);
      if (o < key[r]) key[r] = o;
    }
  }
  if ((threadIdx.x & 63) == 0) {
    const int wid = threadIdx.x >> 6;
    #pragma unroll
    for (int r = 0; r < RPB; r++) red[r][wid] = key[r];
  }
  __syncthreads();
  if (threadIdx.x < 64) {                       // wave 0: 16 lanes per row
    const int r = threadIdx.x >> 4, l = threadIdx.x & 15;
    u64 kk = red[r][l];
    #pragma unroll
    for (int m = 1; m < 16; m <<= 1) {
      const u64 o = __shfl_xor(kk, m);
      if (o < kk) kk = o;
    }
    if (l == 0 && r < nr) {
      const int row  = flags[base + r];
      const int newk = (int)(kk & 0xffffffffULL);
      const int oldk = idx[row];
      if (newk != oldk) {
        idx[row] = newk;
        atomicAdd(&counts[newk],  1.0f);
        atomicAdd(&counts[oldk], -1.0f);
      }
    }
  }
}

// ------------------------------- fused prefix scan (starts/cursor) + cs ----
__global__ __launch_bounds__(1024)
void prefix_cs_kernel(const float* __restrict__ ema_cs, const float* __restrict__ counts,
                      int* __restrict__ starts, int* __restrict__ cursor,
                      float* __restrict__ out_cs, float* __restrict__ cs_ws) {
  __shared__ int sc[1024];
  __shared__ float lds[17];
  const int t = threadIdx.x;
  const int ci = (int)counts[t];
  sc[t] = ci;
  const float c = ema_cs[t] * 0.99f + 0.01f * counts[t];
  float v = c;
  #pragma unroll
  for (int off = 32; off > 0; off >>= 1) v += __shfl_down(v, off);
  if ((t & 63) == 0) lds[t >> 6] = v;
  __syncthreads();
  if (t == 0) {
    float n = 0.0f;
    for (int i = 0; i < 16; i++) n += lds[i];
    lds[16] = n;
  }
  __syncthreads();
  const float n = lds[16];
  const float csv = (c + 1e-5f) / (n + 1024.0f * 1e-5f) * n;
  out_cs[t] = csv;
  cs_ws[t]  = csv;
  #pragma unroll
  for (int off = 1; off < 1024; off <<= 1) {
    const int add = (t >= off) ? sc[t - off] : 0;
    __syncthreads();
    sc[t] += add;
    __syncthreads();
  }
  const int excl = sc[t] - ci;
  starts[t] = excl;
  cursor[t] = excl;
}

// ------------------------------------------------------ bucket scatter ----
__global__ __launch_bounds__(256)
void scatter_kernel(const int* __restrict__ idx, int* __restrict__ cursor,
                    int* __restrict__ bucket) {
  const int row = blockIdx.x * 256 + threadIdx.x;
  const int k = idx[row];
  const int pos = atomicAdd(&cursor[k], 1);
  bucket[pos] = row;
}

// ----------------------------------- per-cluster dw reduction (no atomics) ----
__global__ __launch_bounds__(256)
void dw_bucket_kernel(const float4* __restrict__ x4, const int* __restrict__ bucket,
                      const int* __restrict__ starts, const float* __restrict__ counts,
                      float4* __restrict__ dw4) {
  __shared__ float4 red[4][64];
  const int k   = blockIdx.x;
  const int d4  = threadIdx.x & 63;
  const int rg  = threadIdx.x >> 6;
  const int s   = starts[k];
  const int e   = s + (int)counts[k];
  float4 acc = {0.f, 0.f, 0.f, 0.f};
  for (int i = s + rg; i < e; i += 4) {
    const float4 v = x4[bucket[i] * 64 + d4];
    acc.x += v.x; acc.y += v.y; acc.z += v.z; acc.w += v.w;
  }
  red[rg][d4] = acc;
  __syncthreads();
  if (rg == 0) {
    const float4 a1 = red[1][d4], a2 = red[2][d4], a3 = red[3][d4];
    acc.x += a1.x + a2.x + a3.x;
    acc.y += a1.y + a2.y + a3.y;
    acc.z += a1.z + a2.z + a3.z;
    acc.w += a1.w + a2.w + a3.w;
    dw4[k * 64 + d4] = acc;
  }
}

// ------------------------------------------- quantize + loss (no atomics) ----
__global__ __launch_bounds__(256)
void quant_loss_kernel(const float4* __restrict__ x4,
                       const float4* __restrict__ w4,
                       const int* __restrict__ idx,
                       float4* __restrict__ outq,
                       float* __restrict__ partials) {
  __shared__ float lds[4];
  const int g  = blockIdx.x * 256 + threadIdx.x;
  const int n  = g >> 6;
  const int d4 = g & 63;
  const float4 xv = x4[g];
  const int   k  = idx[n];
  const float4 qv = w4[k * 64 + d4];
  float4 r;
  r.x = xv.x + (qv.x - xv.x);
  r.y = xv.y + (qv.y - xv.y);
  r.z = xv.z + (qv.z - xv.z);
  r.w = xv.w + (qv.w - xv.w);
  outq[g] = r;

  const float dx = xv.x - r.x, dy = xv.y - r.y, dz = xv.z - r.z, dwv = xv.w - r.w;
  float s = dx * dx + dy * dy + dz * dz + dwv * dwv;
  #pragma unroll
  for (int off = 32; off > 0; off >>= 1) s += __shfl_down(s, off);
  if ((threadIdx.x & 63) == 0) lds[threadIdx.x >> 6] = s;
  __syncthreads();
  if (threadIdx.x == 0) partials[blockIdx.x] = lds[0] + lds[1] + lds[2] + lds[3];
}

// --------------------------------- fused ema_w/embed (+ loss finalize) ----
__global__ __launch_bounds__(256)
void emb_loss_kernel(const float* __restrict__ ema_w, const float* __restrict__ dw,
                     const float* __restrict__ cs, const float* __restrict__ partials,
                     float* __restrict__ out_ema_w, float* __restrict__ out_embed,
                     float* __restrict__ out_loss) {
  if (blockIdx.x == 1024) {
    __shared__ float lds[4];
    float s = 0.0f;
    for (int i = threadIdx.x; i < 4096; i += 256) s += partials[i];
    #pragma unroll
    for (int off = 32; off > 0; off >>= 1) s += __shfl_down(s, off);
    if ((threadIdx.x & 63) == 0) lds[threadIdx.x >> 6] = s;
    __syncthreads();
    if (threadIdx.x == 0) {
      const float total = lds[0] + lds[1] + lds[2] + lds[3];
      out_loss[0] = 0.25f * (total / 4194304.0f);
    }
    return;
  }
  const int g = blockIdx.x * 256 + threadIdx.x;
  const int k = g >> 8;
  const float e = ema_w[g] * 0.99f + 0.01f * dw[g];
  out_ema_w[g] = e;
  out_embed[g] = e / cs[k];
}

// ------------------------------------------------------------------ launch ----
extern "C" void kernel_launch(void* const* d_in, const int* in_sizes, int n_in,
                              void* d_out, int out_size, void* d_ws, size_t ws_size,
                              hipStream_t stream) {
  const float* x       = (const float*)d_in[0];
  const float* embed_w = (const float*)d_in[1];
  const float* ema_cs  = (const float*)d_in[2];
  const float* ema_w   = (const float*)d_in[3];

  float* out        = (float*)d_out;
  float* out_q      = out;                 // 4194304
  float* out_loss   = out + 4194304;       // 1
  float* out_embed  = out + 4194305;       // 262144
  float* out_cs     = out + 4456449;       // 1024
  float* out_ema_w  = out + 4457473;       // 262144

  char* ws = (char*)d_ws;
  u64*   pairs    = (u64*)  (ws + 0);           // 2 MB [0, 2097152)
  int*   bucket   = (int*)  (ws + 0);           // 64 KB  (alias, post-merge)
  float* dw       = (float*)(ws + 1048576);     // 1 MB   (alias pairs hi, post-merge)
  int*   idx      = (int*)  (ws + 2097152);     // 64 KB  [2097152, 2162688)
  float* counts   = (float*)(ws + 2162688);     // 4 KB
  int*   counter  = (int*)  (ws + 2166784);     // 4 B (adjacent to counts)
  int*   flags    = (int*)  (ws + 2166912);     // 32 KB
  float* wnorm    = (float*)(ws + 2199680);     // 4 KB
  float* cs_ws    = (float*)(ws + 2203776);     // 4 KB
  float* partials = (float*)(ws + 2207872);     // 16 KB
  int*   starts   = (int*)  (ws + 2224256);     // 4 KB
  int*   cursor   = (int*)  (ws + 2228352);     // 4 KB
  ushort* wh      = (ushort*)(ws + 2232448);    // 512 KB [2232448, 2756736)
  ushort* wl      = (ushort*)(ws + 2756736);    // 512 KB [2756736, 3281024)
  // ^ R8/R10 BUG: wl was at 2756608, overlapping wh's last 128 B (code 1023
  //   hi-plane clobbered by code 0 lo-plane) -> deterministic argmin flips.

  // x planes alias out_q (16 MB exactly; overwritten by quant_loss later).
  ushort* xh = (ushort*)out_q;                  // 8 MB
  ushort* xl = (ushort*)out_q + 4194304;        // 8 MB

  hipMemsetAsync(counts, 0, 4100, stream);      // counts + counter

  pack_wnorm_kernel<<<2180, 256, 0, stream>>>(
      (const float4*)x, (const float4*)embed_w, embed_w,
      (uint4*)xh, (uint4*)xl, (uint4*)wh, (uint4*)wl, wnorm);
  dist_mfma_kernel<<<(NROW / MT) * KSPLIT, 256, 0, stream>>>(xh, xl, wh, wl, wnorm, pairs);
  merge_kernel<<<NROW / 256, 256, 0, stream>>>(pairs, idx, counts, flags, counter);
  recheck_np_kernel<<<FCAP / RPB, 1024, 0, stream>>>(x, embed_w, wnorm, flags, counter,
                                                     idx, counts);
  prefix_cs_kernel<<<1, 1024, 0, stream>>>(ema_cs, counts, starts, cursor, out_cs, cs_ws);
  scatter_kernel<<<NROW / 256, 256, 0, stream>>>(idx, cursor, bucket);
  dw_bucket_kernel<<<KC, 256, 0, stream>>>((const float4*)x, bucket, starts, counts,
                                           (float4*)dw);
  quant_loss_kernel<<<NROW * 64 / 256, 256, 0, stream>>>(
      (const float4*)x, (const float4*)embed_w, idx, (float4*)out_q, partials);
  emb_loss_kernel<<<KC * DIM / 256 + 1, 256, 0, stream>>>(
      ema_w, dw, cs_ws, partials, out_ema_w, out_embed, out_loss);
}

// Round 10
// 189.536 us; speedup vs baseline: 3.4973x; 1.0374x over previous
//
#include <hip/hip_runtime.h>
#include <cstdint>
#include <cstddef>

// Problem constants (B=16, T=1024, D=256, K=1024)
namespace {
constexpr int NROW = 16384;   // B*T
constexpr int KC   = 1024;    // codes
constexpr int DIM  = 256;
constexpr int MT   = 128;     // rows per block (argmin GEMM)
constexpr int KSPLIT = 8;     // codes partitioned across blocks
constexpr int KPB  = KC / KSPLIT;   // 128 codes per block
constexpr int FCAP = 8192;    // flagged-row capacity (expect ~450)
constexpr int RPB  = 4;       // flagged rows per recheck block
}

typedef __attribute__((ext_vector_type(8))) short bf16x8;
typedef __attribute__((ext_vector_type(4))) float f32x4;
typedef unsigned long long u64;
typedef uint32_t u32;

// Monotone float -> uint key (ascending), for packed argmin with index tie-break.
__device__ __forceinline__ unsigned fkey(float s) {
  unsigned u = __float_as_uint(s);
  return ((int)u >= 0) ? (u ^ 0x80000000u) : ~u;
}
__device__ __forceinline__ float unfkey(unsigned u) {
  return __uint_as_float((u & 0x80000000u) ? (u ^ 0x80000000u) : ~u);
}

// Split fp32 a into RNE-bf16 hi + RNE-bf16 of exact residual (low 16 bits each).
__device__ __forceinline__ void split2(float a, u32& h, u32& l) {
  const u32 u  = __float_as_uint(a);
  const u32 rh = (u + 0x7fffu + ((u >> 16) & 1u)) >> 16;
  const float ah = __uint_as_float(rh << 16);
  const float al = a - ah;                      // exact (Sterbenz)
  const u32 v  = __float_as_uint(al);
  const u32 rl = (v + 0x7fffu + ((v >> 16) & 1u)) >> 16;
  h = rh & 0xffffu; l = rl & 0xffffu;
}

// numpy pairwise sum of squares of 256 floats, bit-exact emulation.
__device__ __forceinline__ float np_sumsq_256(const float* __restrict__ p) {
  float half[2];
  #pragma unroll
  for (int h = 0; h < 2; h++) {
    const float* q = p + h * 128;
    float r[8];
    #pragma unroll
    for (int j = 0; j < 8; j++) r[j] = __fmul_rn(q[j], q[j]);
    #pragma unroll 1
    for (int i = 8; i < 128; i += 8)
      #pragma unroll
      for (int j = 0; j < 8; j++)
        r[j] = __fadd_rn(r[j], __fmul_rn(q[i + j], q[i + j]));
    half[h] = __fadd_rn(__fadd_rn(__fadd_rn(r[0], r[1]), __fadd_rn(r[2], r[3])),
                        __fadd_rn(__fadd_rn(r[4], r[5]), __fadd_rn(r[6], r[7])));
  }
  return __fadd_rn(half[0], half[1]);
}

// ------------------------------------------------- pack planes + wnorm ----
// R17: wnorm branch (1024 threads) also zeroes counts+counter — replaces the
// hipMemsetAsync dispatch. pack runs before merge on the stream, so ordering
// is identical to the old memset.
__global__ __launch_bounds__(256)
void pack_wnorm_kernel(const float4* __restrict__ x4, const float4* __restrict__ w4,
                       const float* __restrict__ w,
                       uint4* __restrict__ xh4, uint4* __restrict__ xl4,
                       uint4* __restrict__ wh4, uint4* __restrict__ wl4,
                       float* __restrict__ wnorm,
                       float* __restrict__ counts, int* __restrict__ counter) {
  if (blockIdx.x >= 2176) {
    const int k = (blockIdx.x - 2176) * 256 + threadIdx.x;
    counts[k] = 0.0f;
    if (k == 0) counter[0] = 0;
    wnorm[k] = np_sumsq_256(&w[k * DIM]);
    return;
  }
  const int g = blockIdx.x * 256 + threadIdx.x;
  const float4* src; uint4* dh; uint4* dl; int gg;
  if (g < 524288) { gg = g;          src = x4; dh = xh4; dl = xl4; }
  else            { gg = g - 524288; src = w4; dh = wh4; dl = wl4; }
  const float4 a = src[gg * 2], b = src[gg * 2 + 1];
  u32 h[8], l[8];
  split2(a.x, h[0], l[0]); split2(a.y, h[1], l[1]);
  split2(a.z, h[2], l[2]); split2(a.w, h[3], l[3]);
  split2(b.x, h[4], l[4]); split2(b.y, h[5], l[5]);
  split2(b.z, h[6], l[6]); split2(b.w, h[7], l[7]);
  uint4 H, L;
  H.x = h[0] | (h[1] << 16); H.y = h[2] | (h[3] << 16);
  H.z = h[4] | (h[5] << 16); H.w = h[6] | (h[7] << 16);
  L.x = l[0] | (l[1] << 16); L.y = l[2] | (l[3] << 16);
  L.z = l[4] | (l[5] << 16); L.w = l[6] | (l[7] << 16);
  dh[gg] = H; dl[gg] = L;
}

// ------------------------------------------- split-bf16 MFMA dist + top-2 ----
// KSPLIT=8: block = 128 rows x 128 codes, 32 KB LDS. Lane-contiguous
// global_load_lds staging; XCD swizzle (8 ksplit siblings share bid%8).
// R12: XOR bank swizzle (rule #21: pre-swizzled global source + swizzled
// ds_read, LDS dest linear) + 4 blocks/CU. R13 (dbuf), R14 (counted vmcnt)
// null; R15 (atomic dw), R16 (device-fence fusion) regressed — reverted.
__global__ __launch_bounds__(256, 4)
void dist_mfma_kernel(const ushort* __restrict__ xh, const ushort* __restrict__ xl,
                      const ushort* __restrict__ wh, const ushort* __restrict__ wl,
                      const float* __restrict__ wnorm,
                      u64* __restrict__ pairs) {
  __shared__ __align__(16) u32 lds[8192];   // 32 KB: AH 8K | AL 8K | BH 8K | BL 8K

  const int tid  = threadIdx.x;
  const int lane = tid & 63;
  const int wv   = tid >> 6;
  const int quad = lane >> 4;
  const int idx16 = lane & 15;
  const int bid  = blockIdx.x;
  const int rowBase = (((bid >> 6) << 3) | (bid & 7)) * MT;
  const int sp      = (bid >> 3) & 7;
  const int kbase   = sp * KPB;

  // 32 staging chunks of 1 KB (16 rows x 64 B); wave wv handles 8.
  // Source slot is pre-swizzled: LDS(row, s) holds global(row, s ^ ((row>>1)&3)).
  const int subrow = lane >> 2, grp = lane & 3;
  const int sgrp = grp ^ ((subrow >> 1) & 3);
  const ushort* gptr[8];
  u32 ldst[8];
  #pragma unroll
  for (int j = 0; j < 8; j++) {
    const int c = wv * 8 + j;
    const ushort* plane; int r0; u32 dstB;
    if (c < 8)       { plane = xh + rowBase * DIM; r0 = c * 16;        dstB = c * 1024; }
    else if (c < 16) { plane = xl + rowBase * DIM; r0 = (c - 8) * 16;  dstB = 8192 + (c - 8) * 1024; }
    else if (c < 24) { plane = wh + kbase * DIM;   r0 = (c - 16) * 16; dstB = 16384 + (c - 16) * 1024; }
    else             { plane = wl + kbase * DIM;   r0 = (c - 24) * 16; dstB = 24576 + (c - 24) * 1024; }
    gptr[j] = plane + (r0 + subrow) * DIM + sgrp * 8;
    ldst[j] = dstB >> 2;
  }

  f32x4 acc[2][8];
  #pragma unroll
  for (int rt = 0; rt < 2; rt++)
    #pragma unroll
    for (int ct = 0; ct < 8; ct++) acc[rt][ct] = (f32x4){0.f, 0.f, 0.f, 0.f};

  // Read-side swizzle: both ar and br are ≡ idx16 (mod 16), so the XOR term
  // is uniform per lane across all A/B fragment reads.
  const int slotOff = (quad ^ ((idx16 >> 1) & 3)) * 16;

  #pragma unroll 1
  for (int kc = 0; kc < DIM / 32; kc++) {
    __syncthreads();   // previous readers done
    #pragma unroll
    for (int j = 0; j < 8; j++) {
      __builtin_amdgcn_global_load_lds(
          (const __attribute__((address_space(1))) u32*)(gptr[j]),
          (__attribute__((address_space(3))) u32*)&lds[ldst[j]], 16, 0, 0);
      gptr[j] += 32;   // next 32 K-elems
    }
    __syncthreads();   // drains vmcnt; LDS visible

    bf16x8 Ah[2], Al[2];
    #pragma unroll
    for (int rt = 0; rt < 2; rt++) {
      const int ar = wv * 32 + rt * 16 + idx16;
      Ah[rt] = *(const bf16x8*)((const char*)lds + ar * 64 + slotOff);
      Al[rt] = *(const bf16x8*)((const char*)lds + 8192 + ar * 64 + slotOff);
    }
    #pragma unroll
    for (int ct = 0; ct < 8; ct++) {
      const int br = ct * 16 + idx16;
      const bf16x8 Bh = *(const bf16x8*)((const char*)lds + 16384 + br * 64 + slotOff);
      const bf16x8 Bl = *(const bf16x8*)((const char*)lds + 24576 + br * 64 + slotOff);
      #pragma unroll
      for (int rt = 0; rt < 2; rt++) {
        acc[rt][ct] = __builtin_amdgcn_mfma_f32_16x16x32_bf16(Al[rt], Bh, acc[rt][ct], 0, 0, 0);
        acc[rt][ct] = __builtin_amdgcn_mfma_f32_16x16x32_bf16(Ah[rt], Bl, acc[rt][ct], 0, 0, 0);
        acc[rt][ct] = __builtin_amdgcn_mfma_f32_16x16x32_bf16(Ah[rt], Bh, acc[rt][ct], 0, 0, 0);
      }
    }
  }

  // Epilogue: score = wnorm - 2*dot; per-lane top-2, then 4-stage butterfly.
  u64 b0[2][4], b1[2][4];
  #pragma unroll
  for (int rt = 0; rt < 2; rt++)
    #pragma unroll
    for (int reg = 0; reg < 4; reg++) { b0[rt][reg] = ~0ULL; b1[rt][reg] = ~0ULL; }

  #pragma unroll
  for (int ct = 0; ct < 8; ct++) {
    const int col = kbase + ct * 16 + idx16;
    const float wn = wnorm[col];
    #pragma unroll
    for (int rt = 0; rt < 2; rt++) {
      #pragma unroll
      for (int reg = 0; reg < 4; reg++) {
        const float s = fmaf(-2.0f, acc[rt][ct][reg], wn);
        const u64 p = ((u64)fkey(s) << 32) | (unsigned)col;
        if (p < b1[rt][reg]) {
          if (p < b0[rt][reg]) { b1[rt][reg] = b0[rt][reg]; b0[rt][reg] = p; }
          else                 { b1[rt][reg] = p; }
        }
      }
    }
  }

  #pragma unroll
  for (int m = 1; m <= 8; m <<= 1) {
    #pragma unroll
    for (int rt = 0; rt < 2; rt++) {
      #pragma unroll
      for (int reg = 0; reg < 4; reg++) {
        const u64 o0 = __shfl_xor(b0[rt][reg], m);
        const u64 o1 = __shfl_xor(b1[rt][reg], m);
        if (o0 < b0[rt][reg]) {
          b1[rt][reg] = (b0[rt][reg] < o1) ? b0[rt][reg] : o1;
          b0[rt][reg] = o0;
        } else {
          b1[rt][reg] = (b1[rt][reg] < o0) ? b1[rt][reg] : o0;
        }
      }
    }
  }

  if (idx16 == 0) {
    #pragma unroll
    for (int rt = 0; rt < 2; rt++) {
      #pragma unroll
      for (int reg = 0; reg < 4; reg++) {
        const int row = rowBase + wv * 32 + rt * 16 + quad * 4 + reg;
        pairs[row * 16 + sp * 2 + 0] = b0[rt][reg];
        pairs[row * 16 + sp * 2 + 1] = b1[rt][reg];
      }
    }
  }
}

// ------------------------------------- merge splits + flag + counts ----
__global__ __launch_bounds__(256)
void merge_kernel(const u64* __restrict__ pairs,
                  int* __restrict__ idx, float* __restrict__ counts,
                  int* __restrict__ flags, int* __restrict__ counter) {
  const int row = blockIdx.x * 256 + threadIdx.x;
  const u64* p = &pairs[row * 16];
  u64 B0 = p[0], B1 = p[1];
  #pragma unroll
  for (int s = 1; s < KSPLIT; s++) {
    const u64 c0 = p[s * 2], c1 = p[s * 2 + 1];
    if (c0 < B0) { B1 = (B0 < c1) ? B0 : c1; B0 = c0; }
    else         { B1 = (B1 < c0) ? B1 : c0; }
  }
  const int k = (int)(B0 & 0xffffffffULL);
  idx[row] = k;
  atomicAdd(&counts[k], 1.0f);
  const float s0 = unfkey((unsigned)(B0 >> 32));
  const float s1 = unfkey((unsigned)(B1 >> 32));
  if (s1 - s0 < 2e-4f) {
    const int pos = atomicAdd(counter, 1);
    if (pos < FCAP) flags[pos] = row;
  }
}

// --------------------- np-fp32-emulating recheck; adjusts counts on flips ----
// R11 structure: 1024 threads/block, one code per thread; x rows
// pre-converted to double in LDS once; u64 argmin via wave shfl_xor reduce.
// FMA order per (row,code) unchanged -> bit-identical results.
// NOTE (R16 lesson): __threadfence() on gfx950 = per-XCD L2 writeback
// broadcasts; in a wide grid it cost ~510 us. Never wide device fences.
__global__ __launch_bounds__(1024)
void recheck_np_kernel(const float* __restrict__ x, const float* __restrict__ w,
                       const float* __restrict__ wnorm,
                       const int* __restrict__ flags, const int* __restrict__ counter,
                       int* __restrict__ idx, float* __restrict__ counts) {
  __shared__ float  xs[RPB][DIM];    // 4 KB
  __shared__ double xd[RPB][DIM];    // 8 KB
  __shared__ float  x2sh[RPB];
  __shared__ u64    red[RPB][16];

  const int cnt  = min(*counter, FCAP);
  const int base = blockIdx.x * RPB;
  if (base >= cnt) return;
  const int nr = min(RPB, cnt - base);

  {
    const int r = threadIdx.x >> 8, d = threadIdx.x & 255;
    const float v = (r < nr) ? x[flags[base + r] * DIM + d] : 0.0f;
    xs[r][d] = v;
    xd[r][d] = (double)v;
  }
  __syncthreads();
  if (threadIdx.x < RPB) x2sh[threadIdx.x] = np_sumsq_256(xs[threadIdx.x]);
  __syncthreads();

  double x2d[RPB];
  #pragma unroll
  for (int r = 0; r < RPB; r++) x2d[r] = (double)x2sh[r];

  const int k = threadIdx.x;                    // one code per thread
  const float* __restrict__ wr = &w[k * DIM];
  const double w2 = (double)wnorm[k];

  double dot[RPB];
  #pragma unroll
  for (int r = 0; r < RPB; r++) dot[r] = 0.0;

  float4 wv[4];
  #pragma unroll
  for (int q = 0; q < 4; q++) wv[q] = *(const float4*)&wr[q * 4];

  #pragma unroll 1
  for (int d = 0; d < DIM; d += 16) {
    float4 cur[4];
    #pragma unroll
    for (int q = 0; q < 4; q++) cur[q] = wv[q];
    if (d + 16 < DIM) {
      #pragma unroll
      for (int q = 0; q < 4; q++) wv[q] = *(const float4*)&wr[d + 16 + q * 4];
    }
    #pragma unroll
    for (int q = 0; q < 4; q++) {
      const double wa = (double)cur[q].x, wb = (double)cur[q].y,
                   wc = (double)cur[q].z, wd_ = (double)cur[q].w;
      #pragma unroll
      for (int r = 0; r < RPB; r++) {
        dot[r] = fma(xd[r][d + q * 4 + 0], wa,  dot[r]);
        dot[r] = fma(xd[r][d + q * 4 + 1], wb,  dot[r]);
        dot[r] = fma(xd[r][d + q * 4 + 2], wc,  dot[r]);
        dot[r] = fma(xd[r][d + q * 4 + 3], wd_, dot[r]);
      }
    }
  }

  u64 key[RPB];
  #pragma unroll
  for (int r = 0; r < RPB; r++) {
    const float mmf = (float)dot[r];
    const float S1  = (float)(x2d[r] + w2);
    const float D   = (float)((double)S1 - 2.0 * (double)mmf);
    key[r] = ((u64)fkey(D) << 32) | (unsigned)k;
  }

  // wave-level u64 min (6 butterfly stages)
  #pragma unroll
  for (int m = 1; m < 64; m <<= 1) {
    #pragma unroll
    for (int r = 0; r < RPB; r++) {
      const u64 o = __shfl_xor(key[r], m);
      if (o < key[r]) key[r] = o;
    }
  }
  if ((threadIdx.x & 63) == 0) {
    const int wid = threadIdx.x >> 6;
    #pragma unroll
    for (int r = 0; r < RPB; r++) red[r][wid] = key[r];
  }
  __syncthreads();
  if (threadIdx.x < 64) {                       // wave 0: 16 lanes per row
    const int r = threadIdx.x >> 4, l = threadIdx.x & 15;
    u64 kk = red[r][l];
    #pragma unroll
    for (int m = 1; m < 16; m <<= 1) {
      const u64 o = __shfl_xor(kk, m);
      if (o < kk) kk = o;
    }
    if (l == 0 && r < nr) {
      const int row  = flags[base + r];
      const int newk = (int)(kk & 0xffffffffULL);
      const int oldk = idx[row];
      if (newk != oldk) {
        idx[row] = newk;
        atomicAdd(&counts[newk],  1.0f);
        atomicAdd(&counts[oldk], -1.0f);
      }
    }
  }
}

// ------------------------------- fused prefix scan (starts/cursor) + cs ----
__global__ __launch_bounds__(1024)
void prefix_cs_kernel(const float* __restrict__ ema_cs, const float* __restrict__ counts,
                      int* __restrict__ starts, int* __restrict__ cursor,
                      float* __restrict__ out_cs, float* __restrict__ cs_ws) {
  __shared__ int sc[1024];
  __shared__ float lds[17];
  const int t = threadIdx.x;
  const int ci = (int)counts[t];
  sc[t] = ci;
  const float c = ema_cs[t] * 0.99f + 0.01f * counts[t];
  float v = c;
  #pragma unroll
  for (int off = 32; off > 0; off >>= 1) v += __shfl_down(v, off);
  if ((t & 63) == 0) lds[t >> 6] = v;
  __syncthreads();
  if (t == 0) {
    float n = 0.0f;
    for (int i = 0; i < 16; i++) n += lds[i];
    lds[16] = n;
  }
  __syncthreads();
  const float n = lds[16];
  const float csv = (c + 1e-5f) / (n + 1024.0f * 1e-5f) * n;
  out_cs[t] = csv;
  cs_ws[t]  = csv;
  #pragma unroll
  for (int off = 1; off < 1024; off <<= 1) {
    const int add = (t >= off) ? sc[t - off] : 0;
    __syncthreads();
    sc[t] += add;
    __syncthreads();
  }
  const int excl = sc[t] - ci;
  starts[t] = excl;
  cursor[t] = excl;
}

// -------------- quantize + loss + bucket scatter (R17 fusion, no fences) ----
// The d4==0 lane of each row (one per row, 16384 total — same atomic count
// as the old scatter_kernel) appends its row to the cluster bucket. Bucket
// order within a cluster changes vs the old scatter, but it was already
// nondeterministic (atomic cursor); only permutes dw summation order.
__global__ __launch_bounds__(256)
void quant_loss_kernel(const float4* __restrict__ x4,
                       const float4* __restrict__ w4,
                       const int* __restrict__ idx,
                       float4* __restrict__ outq,
                       float* __restrict__ partials,
                       int* __restrict__ cursor, int* __restrict__ bucket) {
  __shared__ float lds[4];
  const int g  = blockIdx.x * 256 + threadIdx.x;
  const int n  = g >> 6;
  const int d4 = g & 63;
  const float4 xv = x4[g];
  const int   k  = idx[n];
  if (d4 == 0) {
    const int pos = atomicAdd(&cursor[k], 1);
    bucket[pos] = n;
  }
  const float4 qv = w4[k * 64 + d4];
  float4 r;
  r.x = xv.x + (qv.x - xv.x);
  r.y = xv.y + (qv.y - xv.y);
  r.z = xv.z + (qv.z - xv.z);
  r.w = xv.w + (qv.w - xv.w);
  outq[g] = r;

  const float dx = xv.x - r.x, dy = xv.y - r.y, dz = xv.z - r.z, dwv = xv.w - r.w;
  float s = dx * dx + dy * dy + dz * dz + dwv * dwv;
  #pragma unroll
  for (int off = 32; off > 0; off >>= 1) s += __shfl_down(s, off);
  if ((threadIdx.x & 63) == 0) lds[threadIdx.x >> 6] = s;
  __syncthreads();
  if (threadIdx.x == 0) partials[blockIdx.x] = lds[0] + lds[1] + lds[2] + lds[3];
}

// ----------------------------------- per-cluster dw reduction (no atomics) ----
__global__ __launch_bounds__(256)
void dw_bucket_kernel(const float4* __restrict__ x4, const int* __restrict__ bucket,
                      const int* __restrict__ starts, const float* __restrict__ counts,
                      float4* __restrict__ dw4) {
  __shared__ float4 red[4][64];
  const int k   = blockIdx.x;
  const int d4  = threadIdx.x & 63;
  const int rg  = threadIdx.x >> 6;
  const int s   = starts[k];
  const int e   = s + (int)counts[k];
  float4 acc = {0.f, 0.f, 0.f, 0.f};
  for (int i = s + rg; i < e; i += 4) {
    const float4 v = x4[bucket[i] * 64 + d4];
    acc.x += v.x; acc.y += v.y; acc.z += v.z; acc.w += v.w;
  }
  red[rg][d4] = acc;
  __syncthreads();
  if (rg == 0) {
    const float4 a1 = red[1][d4], a2 = red[2][d4], a3 = red[3][d4];
    acc.x += a1.x + a2.x + a3.x;
    acc.y += a1.y + a2.y + a3.y;
    acc.z += a1.z + a2.z + a3.z;
    acc.w += a1.w + a2.w + a3.w;
    dw4[k * 64 + d4] = acc;
  }
}

// --------------------------------- fused ema_w/embed (+ loss finalize) ----
__global__ __launch_bounds__(256)
void emb_loss_kernel(const float* __restrict__ ema_w, const float* __restrict__ dw,
                     const float* __restrict__ cs, const float* __restrict__ partials,
                     float* __restrict__ out_ema_w, float* __restrict__ out_embed,
                     float* __restrict__ out_loss) {
  if (blockIdx.x == 1024) {
    __shared__ float lds[4];
    float s = 0.0f;
    for (int i = threadIdx.x; i < 4096; i += 256) s += partials[i];
    #pragma unroll
    for (int off = 32; off > 0; off >>= 1) s += __shfl_down(s, off);
    if ((threadIdx.x & 63) == 0) lds[threadIdx.x >> 6] = s;
    __syncthreads();
    if (threadIdx.x == 0) {
      const float total = lds[0] + lds[1] + lds[2] + lds[3];
      out_loss[0] = 0.25f * (total / 4194304.0f);
    }
    return;
  }
  const int g = blockIdx.x * 256 + threadIdx.x;
  const int k = g >> 8;
  const float e = ema_w[g] * 0.99f + 0.01f * dw[g];
  out_ema_w[g] = e;
  out_embed[g] = e / cs[k];
}

// ------------------------------------------------------------------ launch ----
extern "C" void kernel_launch(void* const* d_in, const int* in_sizes, int n_in,
                              void* d_out, int out_size, void* d_ws, size_t ws_size,
                              hipStream_t stream) {
  const float* x       = (const float*)d_in[0];
  const float* embed_w = (const float*)d_in[1];
  const float* ema_cs  = (const float*)d_in[2];
  const float* ema_w   = (const float*)d_in[3];

  float* out        = (float*)d_out;
  float* out_q      = out;                 // 4194304
  float* out_loss   = out + 4194304;       // 1
  float* out_embed  = out + 4194305;       // 262144
  float* out_cs     = out + 4456449;       // 1024
  float* out_ema_w  = out + 4457473;       // 262144

  char* ws = (char*)d_ws;
  u64*   pairs    = (u64*)  (ws + 0);           // 2 MB [0, 2097152)
  int*   bucket   = (int*)  (ws + 0);           // 64 KB  (alias, post-merge)
  float* dw       = (float*)(ws + 1048576);     // 1 MB   (alias pairs hi, post-merge)
  int*   idx      = (int*)  (ws + 2097152);     // 64 KB  [2097152, 2162688)
  float* counts   = (float*)(ws + 2162688);     // 4 KB
  int*   counter  = (int*)  (ws + 2166784);     // 4 B (adjacent to counts)
  int*   flags    = (int*)  (ws + 2166912);     // 32 KB
  float* wnorm    = (float*)(ws + 2199680);     // 4 KB
  float* cs_ws    = (float*)(ws + 2203776);     // 4 KB
  float* partials = (float*)(ws + 2207872);     // 16 KB
  int*   starts   = (int*)  (ws + 2224256);     // 4 KB
  int*   cursor   = (int*)  (ws + 2228352);     // 4 KB
  ushort* wh      = (ushort*)(ws + 2232448);    // 512 KB [2232448, 2756736)
  ushort* wl      = (ushort*)(ws + 2756736);    // 512 KB [2756736, 3281024)
  // ^ R8/R10 BUG: wl was at 2756608, overlapping wh's last 128 B (code 1023
  //   hi-plane clobbered by code 0 lo-plane) -> deterministic argmin flips.

  // x planes alias out_q (16 MB exactly; overwritten by quant_loss later).
  ushort* xh = (ushort*)out_q;                  // 8 MB
  ushort* xl = (ushort*)out_q + 4194304;        // 8 MB

  pack_wnorm_kernel<<<2180, 256, 0, stream>>>(
      (const float4*)x, (const float4*)embed_w, embed_w,
      (uint4*)xh, (uint4*)xl, (uint4*)wh, (uint4*)wl, wnorm, counts, counter);
  dist_mfma_kernel<<<(NROW / MT) * KSPLIT, 256, 0, stream>>>(xh, xl, wh, wl, wnorm, pairs);
  merge_kernel<<<NROW / 256, 256, 0, stream>>>(pairs, idx, counts, flags, counter);
  recheck_np_kernel<<<FCAP / RPB, 1024, 0, stream>>>(x, embed_w, wnorm, flags, counter,
                                                     idx, counts);
  prefix_cs_kernel<<<1, 1024, 0, stream>>>(ema_cs, counts, starts, cursor, out_cs, cs_ws);
  quant_loss_kernel<<<NROW * 64 / 256, 256, 0, stream>>>(
      (const float4*)x, (const float4*)embed_w, idx, (float4*)out_q, partials,
      cursor, bucket);
  dw_bucket_kernel<<<KC, 256, 0, stream>>>((const float4*)x, bucket, starts, counts,
                                           (float4*)dw);
  emb_loss_kernel<<<KC * DIM / 256 + 1, 256, 0, stream>>>(
      ema_w, dw, cs_ws, partials, out_ema_w, out_embed, out_loss);
}

// Round 11
// 185.201 us; speedup vs baseline: 3.5791x; 1.0234x over previous
//
#include <hip/hip_runtime.h>
#include <cstdint>
#include <cstddef>

// Problem constants (B=16, T=1024, D=256, K=1024)
namespace {
constexpr int NROW = 16384;   // B*T
constexpr int KC   = 1024;    // codes
constexpr int DIM  = 256;
constexpr int MT   = 128;     // rows per block (argmin GEMM)
constexpr int KSPLIT = 8;     // codes partitioned across blocks
constexpr int KPB  = KC / KSPLIT;   // 128 codes per block
constexpr int FCAP = 8192;    // flagged-row capacity (expect ~450)
constexpr int RPB  = 4;       // flagged rows per recheck block
}

typedef __attribute__((ext_vector_type(8))) short bf16x8;
typedef __attribute__((ext_vector_type(4))) float f32x4;
typedef unsigned long long u64;
typedef uint32_t u32;

// Monotone float -> uint key (ascending), for packed argmin with index tie-break.
__device__ __forceinline__ unsigned fkey(float s) {
  unsigned u = __float_as_uint(s);
  return ((int)u >= 0) ? (u ^ 0x80000000u) : ~u;
}
__device__ __forceinline__ float unfkey(unsigned u) {
  return __uint_as_float((u & 0x80000000u) ? (u ^ 0x80000000u) : ~u);
}

// Split fp32 a into RNE-bf16 hi + RNE-bf16 of exact residual (low 16 bits each).
__device__ __forceinline__ void split2(float a, u32& h, u32& l) {
  const u32 u  = __float_as_uint(a);
  const u32 rh = (u + 0x7fffu + ((u >> 16) & 1u)) >> 16;
  const float ah = __uint_as_float(rh << 16);
  const float al = a - ah;                      // exact (Sterbenz)
  const u32 v  = __float_as_uint(al);
  const u32 rl = (v + 0x7fffu + ((v >> 16) & 1u)) >> 16;
  h = rh & 0xffffu; l = rl & 0xffffu;
}

// numpy pairwise sum of squares of 256 floats, bit-exact emulation.
__device__ __forceinline__ float np_sumsq_256(const float* __restrict__ p) {
  float half[2];
  #pragma unroll
  for (int h = 0; h < 2; h++) {
    const float* q = p + h * 128;
    float r[8];
    #pragma unroll
    for (int j = 0; j < 8; j++) r[j] = __fmul_rn(q[j], q[j]);
    #pragma unroll 1
    for (int i = 8; i < 128; i += 8)
      #pragma unroll
      for (int j = 0; j < 8; j++)
        r[j] = __fadd_rn(r[j], __fmul_rn(q[i + j], q[i + j]));
    half[h] = __fadd_rn(__fadd_rn(__fadd_rn(r[0], r[1]), __fadd_rn(r[2], r[3])),
                        __fadd_rn(__fadd_rn(r[4], r[5]), __fadd_rn(r[6], r[7])));
  }
  return __fadd_rn(half[0], half[1]);
}

// ------------------------------------------------- pack planes + wnorm ----
// R17: wnorm branch (1024 threads) also zeroes counts+counter — replaces the
// hipMemsetAsync dispatch. pack runs before merge on the stream, so ordering
// is identical to the old memset.
__global__ __launch_bounds__(256)
void pack_wnorm_kernel(const float4* __restrict__ x4, const float4* __restrict__ w4,
                       const float* __restrict__ w,
                       uint4* __restrict__ xh4, uint4* __restrict__ xl4,
                       uint4* __restrict__ wh4, uint4* __restrict__ wl4,
                       float* __restrict__ wnorm,
                       float* __restrict__ counts, int* __restrict__ counter) {
  if (blockIdx.x >= 2176) {
    const int k = (blockIdx.x - 2176) * 256 + threadIdx.x;
    counts[k] = 0.0f;
    if (k == 0) counter[0] = 0;
    wnorm[k] = np_sumsq_256(&w[k * DIM]);
    return;
  }
  const int g = blockIdx.x * 256 + threadIdx.x;
  const float4* src; uint4* dh; uint4* dl; int gg;
  if (g < 524288) { gg = g;          src = x4; dh = xh4; dl = xl4; }
  else            { gg = g - 524288; src = w4; dh = wh4; dl = wl4; }
  const float4 a = src[gg * 2], b = src[gg * 2 + 1];
  u32 h[8], l[8];
  split2(a.x, h[0], l[0]); split2(a.y, h[1], l[1]);
  split2(a.z, h[2], l[2]); split2(a.w, h[3], l[3]);
  split2(b.x, h[4], l[4]); split2(b.y, h[5], l[5]);
  split2(b.z, h[6], l[6]); split2(b.w, h[7], l[7]);
  uint4 H, L;
  H.x = h[0] | (h[1] << 16); H.y = h[2] | (h[3] << 16);
  H.z = h[4] | (h[5] << 16); H.w = h[6] | (h[7] << 16);
  L.x = l[0] | (l[1] << 16); L.y = l[2] | (l[3] << 16);
  L.z = l[4] | (l[5] << 16); L.w = l[6] | (l[7] << 16);
  dh[gg] = H; dl[gg] = L;
}

// ------------------------------------------- split-bf16 MFMA dist + top-2 ----
// KSPLIT=8: block = 128 rows x 128 codes, 32 KB LDS. Lane-contiguous
// global_load_lds staging; XCD swizzle (8 ksplit siblings share bid%8).
// R12: XOR bank swizzle (rule #21: pre-swizzled global source + swizzled
// ds_read, LDS dest linear) + 4 blocks/CU. R13 (dbuf), R14 (counted vmcnt)
// null; R15 (atomic dw), R16 (device-fence fusion) regressed — reverted.
__global__ __launch_bounds__(256, 4)
void dist_mfma_kernel(const ushort* __restrict__ xh, const ushort* __restrict__ xl,
                      const ushort* __restrict__ wh, const ushort* __restrict__ wl,
                      const float* __restrict__ wnorm,
                      u64* __restrict__ pairs) {
  __shared__ __align__(16) u32 lds[8192];   // 32 KB: AH 8K | AL 8K | BH 8K | BL 8K

  const int tid  = threadIdx.x;
  const int lane = tid & 63;
  const int wv   = tid >> 6;
  const int quad = lane >> 4;
  const int idx16 = lane & 15;
  const int bid  = blockIdx.x;
  const int rowBase = (((bid >> 6) << 3) | (bid & 7)) * MT;
  const int sp      = (bid >> 3) & 7;
  const int kbase   = sp * KPB;

  // 32 staging chunks of 1 KB (16 rows x 64 B); wave wv handles 8.
  // Source slot is pre-swizzled: LDS(row, s) holds global(row, s ^ ((row>>1)&3)).
  const int subrow = lane >> 2, grp = lane & 3;
  const int sgrp = grp ^ ((subrow >> 1) & 3);
  const ushort* gptr[8];
  u32 ldst[8];
  #pragma unroll
  for (int j = 0; j < 8; j++) {
    const int c = wv * 8 + j;
    const ushort* plane; int r0; u32 dstB;
    if (c < 8)       { plane = xh + rowBase * DIM; r0 = c * 16;        dstB = c * 1024; }
    else if (c < 16) { plane = xl + rowBase * DIM; r0 = (c - 8) * 16;  dstB = 8192 + (c - 8) * 1024; }
    else if (c < 24) { plane = wh + kbase * DIM;   r0 = (c - 16) * 16; dstB = 16384 + (c - 16) * 1024; }
    else             { plane = wl + kbase * DIM;   r0 = (c - 24) * 16; dstB = 24576 + (c - 24) * 1024; }
    gptr[j] = plane + (r0 + subrow) * DIM + sgrp * 8;
    ldst[j] = dstB >> 2;
  }

  f32x4 acc[2][8];
  #pragma unroll
  for (int rt = 0; rt < 2; rt++)
    #pragma unroll
    for (int ct = 0; ct < 8; ct++) acc[rt][ct] = (f32x4){0.f, 0.f, 0.f, 0.f};

  // Read-side swizzle: both ar and br are ≡ idx16 (mod 16), so the XOR term
  // is uniform per lane across all A/B fragment reads.
  const int slotOff = (quad ^ ((idx16 >> 1) & 3)) * 16;

  #pragma unroll 1
  for (int kc = 0; kc < DIM / 32; kc++) {
    __syncthreads();   // previous readers done
    #pragma unroll
    for (int j = 0; j < 8; j++) {
      __builtin_amdgcn_global_load_lds(
          (const __attribute__((address_space(1))) u32*)(gptr[j]),
          (__attribute__((address_space(3))) u32*)&lds[ldst[j]], 16, 0, 0);
      gptr[j] += 32;   // next 32 K-elems
    }
    __syncthreads();   // drains vmcnt; LDS visible

    bf16x8 Ah[2], Al[2];
    #pragma unroll
    for (int rt = 0; rt < 2; rt++) {
      const int ar = wv * 32 + rt * 16 + idx16;
      Ah[rt] = *(const bf16x8*)((const char*)lds + ar * 64 + slotOff);
      Al[rt] = *(const bf16x8*)((const char*)lds + 8192 + ar * 64 + slotOff);
    }
    #pragma unroll
    for (int ct = 0; ct < 8; ct++) {
      const int br = ct * 16 + idx16;
      const bf16x8 Bh = *(const bf16x8*)((const char*)lds + 16384 + br * 64 + slotOff);
      const bf16x8 Bl = *(const bf16x8*)((const char*)lds + 24576 + br * 64 + slotOff);
      #pragma unroll
      for (int rt = 0; rt < 2; rt++) {
        acc[rt][ct] = __builtin_amdgcn_mfma_f32_16x16x32_bf16(Al[rt], Bh, acc[rt][ct], 0, 0, 0);
        acc[rt][ct] = __builtin_amdgcn_mfma_f32_16x16x32_bf16(Ah[rt], Bl, acc[rt][ct], 0, 0, 0);
        acc[rt][ct] = __builtin_amdgcn_mfma_f32_16x16x32_bf16(Ah[rt], Bh, acc[rt][ct], 0, 0, 0);
      }
    }
  }

  // Epilogue: score = wnorm - 2*dot; per-lane top-2, then 4-stage butterfly.
  u64 b0[2][4], b1[2][4];
  #pragma unroll
  for (int rt = 0; rt < 2; rt++)
    #pragma unroll
    for (int reg = 0; reg < 4; reg++) { b0[rt][reg] = ~0ULL; b1[rt][reg] = ~0ULL; }

  #pragma unroll
  for (int ct = 0; ct < 8; ct++) {
    const int col = kbase + ct * 16 + idx16;
    const float wn = wnorm[col];
    #pragma unroll
    for (int rt = 0; rt < 2; rt++) {
      #pragma unroll
      for (int reg = 0; reg < 4; reg++) {
        const float s = fmaf(-2.0f, acc[rt][ct][reg], wn);
        const u64 p = ((u64)fkey(s) << 32) | (unsigned)col;
        if (p < b1[rt][reg]) {
          if (p < b0[rt][reg]) { b1[rt][reg] = b0[rt][reg]; b0[rt][reg] = p; }
          else                 { b1[rt][reg] = p; }
        }
      }
    }
  }

  #pragma unroll
  for (int m = 1; m <= 8; m <<= 1) {
    #pragma unroll
    for (int rt = 0; rt < 2; rt++) {
      #pragma unroll
      for (int reg = 0; reg < 4; reg++) {
        const u64 o0 = __shfl_xor(b0[rt][reg], m);
        const u64 o1 = __shfl_xor(b1[rt][reg], m);
        if (o0 < b0[rt][reg]) {
          b1[rt][reg] = (b0[rt][reg] < o1) ? b0[rt][reg] : o1;
          b0[rt][reg] = o0;
        } else {
          b1[rt][reg] = (b1[rt][reg] < o0) ? b1[rt][reg] : o0;
        }
      }
    }
  }

  if (idx16 == 0) {
    #pragma unroll
    for (int rt = 0; rt < 2; rt++) {
      #pragma unroll
      for (int reg = 0; reg < 4; reg++) {
        const int row = rowBase + wv * 32 + rt * 16 + quad * 4 + reg;
        pairs[row * 16 + sp * 2 + 0] = b0[rt][reg];
        pairs[row * 16 + sp * 2 + 1] = b1[rt][reg];
      }
    }
  }
}

// ------------------------------------- merge splits + flag + counts ----
__global__ __launch_bounds__(256)
void merge_kernel(const u64* __restrict__ pairs,
                  int* __restrict__ idx, float* __restrict__ counts,
                  int* __restrict__ flags, int* __restrict__ counter) {
  const int row = blockIdx.x * 256 + threadIdx.x;
  const u64* p = &pairs[row * 16];
  u64 B0 = p[0], B1 = p[1];
  #pragma unroll
  for (int s = 1; s < KSPLIT; s++) {
    const u64 c0 = p[s * 2], c1 = p[s * 2 + 1];
    if (c0 < B0) { B1 = (B0 < c1) ? B0 : c1; B0 = c0; }
    else         { B1 = (B1 < c0) ? B1 : c0; }
  }
  const int k = (int)(B0 & 0xffffffffULL);
  idx[row] = k;
  atomicAdd(&counts[k], 1.0f);
  const float s0 = unfkey((unsigned)(B0 >> 32));
  const float s1 = unfkey((unsigned)(B1 >> 32));
  if (s1 - s0 < 2e-4f) {
    const int pos = atomicAdd(counter, 1);
    if (pos < FCAP) flags[pos] = row;
  }
}

// --------------------- np-fp32-emulating recheck; adjusts counts on flips ----
// R11 structure: 1024 threads/block, one code per thread; x rows
// pre-converted to double in LDS once; u64 argmin via wave shfl_xor reduce.
// FMA order per (row,code) unchanged -> bit-identical results.
// NOTE (R16 lesson): __threadfence() on gfx950 = per-XCD L2 writeback
// broadcasts; in a wide grid it cost ~510 us. Never wide device fences.
__global__ __launch_bounds__(1024)
void recheck_np_kernel(const float* __restrict__ x, const float* __restrict__ w,
                       const float* __restrict__ wnorm,
                       const int* __restrict__ flags, const int* __restrict__ counter,
                       int* __restrict__ idx, float* __restrict__ counts) {
  __shared__ float  xs[RPB][DIM];    // 4 KB
  __shared__ double xd[RPB][DIM];    // 8 KB
  __shared__ float  x2sh[RPB];
  __shared__ u64    red[RPB][16];

  const int cnt  = min(*counter, FCAP);
  const int base = blockIdx.x * RPB;
  if (base >= cnt) return;
  const int nr = min(RPB, cnt - base);

  {
    const int r = threadIdx.x >> 8, d = threadIdx.x & 255;
    const float v = (r < nr) ? x[flags[base + r] * DIM + d] : 0.0f;
    xs[r][d] = v;
    xd[r][d] = (double)v;
  }
  __syncthreads();
  if (threadIdx.x < RPB) x2sh[threadIdx.x] = np_sumsq_256(xs[threadIdx.x]);
  __syncthreads();

  double x2d[RPB];
  #pragma unroll
  for (int r = 0; r < RPB; r++) x2d[r] = (double)x2sh[r];

  const int k = threadIdx.x;                    // one code per thread
  const float* __restrict__ wr = &w[k * DIM];
  const double w2 = (double)wnorm[k];

  double dot[RPB];
  #pragma unroll
  for (int r = 0; r < RPB; r++) dot[r] = 0.0;

  float4 wv[4];
  #pragma unroll
  for (int q = 0; q < 4; q++) wv[q] = *(const float4*)&wr[q * 4];

  #pragma unroll 1
  for (int d = 0; d < DIM; d += 16) {
    float4 cur[4];
    #pragma unroll
    for (int q = 0; q < 4; q++) cur[q] = wv[q];
    if (d + 16 < DIM) {
      #pragma unroll
      for (int q = 0; q < 4; q++) wv[q] = *(const float4*)&wr[d + 16 + q * 4];
    }
    #pragma unroll
    for (int q = 0; q < 4; q++) {
      const double wa = (double)cur[q].x, wb = (double)cur[q].y,
                   wc = (double)cur[q].z, wd_ = (double)cur[q].w;
      #pragma unroll
      for (int r = 0; r < RPB; r++) {
        dot[r] = fma(xd[r][d + q * 4 + 0], wa,  dot[r]);
        dot[r] = fma(xd[r][d + q * 4 + 1], wb,  dot[r]);
        dot[r] = fma(xd[r][d + q * 4 + 2], wc,  dot[r]);
        dot[r] = fma(xd[r][d + q * 4 + 3], wd_, dot[r]);
      }
    }
  }

  u64 key[RPB];
  #pragma unroll
  for (int r = 0; r < RPB; r++) {
    const float mmf = (float)dot[r];
    const float S1  = (float)(x2d[r] + w2);
    const float D   = (float)((double)S1 - 2.0 * (double)mmf);
    key[r] = ((u64)fkey(D) << 32) | (unsigned)k;
  }

  // wave-level u64 min (6 butterfly stages)
  #pragma unroll
  for (int m = 1; m < 64; m <<= 1) {
    #pragma unroll
    for (int r = 0; r < RPB; r++) {
      const u64 o = __shfl_xor(key[r], m);
      if (o < key[r]) key[r] = o;
    }
  }
  if ((threadIdx.x & 63) == 0) {
    const int wid = threadIdx.x >> 6;
    #pragma unroll
    for (int r = 0; r < RPB; r++) red[r][wid] = key[r];
  }
  __syncthreads();
  if (threadIdx.x < 64) {                       // wave 0: 16 lanes per row
    const int r = threadIdx.x >> 4, l = threadIdx.x & 15;
    u64 kk = red[r][l];
    #pragma unroll
    for (int m = 1; m < 16; m <<= 1) {
      const u64 o = __shfl_xor(kk, m);
      if (o < kk) kk = o;
    }
    if (l == 0 && r < nr) {
      const int row  = flags[base + r];
      const int newk = (int)(kk & 0xffffffffULL);
      const int oldk = idx[row];
      if (newk != oldk) {
        idx[row] = newk;
        atomicAdd(&counts[newk],  1.0f);
        atomicAdd(&counts[oldk], -1.0f);
      }
    }
  }
}

// ------------------------------- fused prefix scan (starts/cursor) + cs ----
__global__ __launch_bounds__(1024)
void prefix_cs_kernel(const float* __restrict__ ema_cs, const float* __restrict__ counts,
                      int* __restrict__ starts, int* __restrict__ cursor,
                      float* __restrict__ out_cs, float* __restrict__ cs_ws) {
  __shared__ int sc[1024];
  __shared__ float lds[17];
  const int t = threadIdx.x;
  const int ci = (int)counts[t];
  sc[t] = ci;
  const float c = ema_cs[t] * 0.99f + 0.01f * counts[t];
  float v = c;
  #pragma unroll
  for (int off = 32; off > 0; off >>= 1) v += __shfl_down(v, off);
  if ((t & 63) == 0) lds[t >> 6] = v;
  __syncthreads();
  if (t == 0) {
    float n = 0.0f;
    for (int i = 0; i < 16; i++) n += lds[i];
    lds[16] = n;
  }
  __syncthreads();
  const float n = lds[16];
  const float csv = (c + 1e-5f) / (n + 1024.0f * 1e-5f) * n;
  out_cs[t] = csv;
  cs_ws[t]  = csv;
  #pragma unroll
  for (int off = 1; off < 1024; off <<= 1) {
    const int add = (t >= off) ? sc[t - off] : 0;
    __syncthreads();
    sc[t] += add;
    __syncthreads();
  }
  const int excl = sc[t] - ci;
  starts[t] = excl;
  cursor[t] = excl;
}

// -------------- quantize + loss + bucket scatter (R17 fusion, no fences) ----
// The d4==0 lane of each row (one per row, 16384 total — same atomic count
// as the old scatter_kernel) appends its row to the cluster bucket. Bucket
// order within a cluster changes vs the old scatter, but it was already
// nondeterministic (atomic cursor); only permutes dw summation order.
__global__ __launch_bounds__(256)
void quant_loss_kernel(const float4* __restrict__ x4,
                       const float4* __restrict__ w4,
                       const int* __restrict__ idx,
                       float4* __restrict__ outq,
                       float* __restrict__ partials,
                       int* __restrict__ cursor, int* __restrict__ bucket) {
  __shared__ float lds[4];
  const int g  = blockIdx.x * 256 + threadIdx.x;
  const int n  = g >> 6;
  const int d4 = g & 63;
  const float4 xv = x4[g];
  const int   k  = idx[n];
  if (d4 == 0) {
    const int pos = atomicAdd(&cursor[k], 1);
    bucket[pos] = n;
  }
  const float4 qv = w4[k * 64 + d4];
  float4 r;
  r.x = xv.x + (qv.x - xv.x);
  r.y = xv.y + (qv.y - xv.y);
  r.z = xv.z + (qv.z - xv.z);
  r.w = xv.w + (qv.w - xv.w);
  outq[g] = r;

  const float dx = xv.x - r.x, dy = xv.y - r.y, dz = xv.z - r.z, dwv = xv.w - r.w;
  float s = dx * dx + dy * dy + dz * dz + dwv * dwv;
  #pragma unroll
  for (int off = 32; off > 0; off >>= 1) s += __shfl_down(s, off);
  if ((threadIdx.x & 63) == 0) lds[threadIdx.x >> 6] = s;
  __syncthreads();
  if (threadIdx.x == 0) partials[blockIdx.x] = lds[0] + lds[1] + lds[2] + lds[3];
}

// ------- per-cluster dw reduction + fused ema_w/embed + loss (R18) ----
// R18: emb_loss fused into dw_bucket. Block k holds dw[k]'s 256 values in
// registers after the LDS reduction (rg==0 threads, float4 each) — apply
// ema_w*0.99+0.01*dw and /cs[k] directly; dw never touches memory. Loss
// finalize moved to extra block KC (partials complete: quant_loss precedes
// on stream). Scalar stores: out_embed/out_ema_w sit at odd float offsets.
// Math bit-identical to the former emb_loss (acc == dw[g] it used to read).
__global__ __launch_bounds__(256)
void dw_emb_kernel(const float4* __restrict__ x4, const int* __restrict__ bucket,
                   const int* __restrict__ starts, const float* __restrict__ counts,
                   const float* __restrict__ ema_w, const float* __restrict__ cs,
                   const float* __restrict__ partials,
                   float* __restrict__ out_ema_w, float* __restrict__ out_embed,
                   float* __restrict__ out_loss) {
  if (blockIdx.x == KC) {   // loss finalize
    __shared__ float lds[4];
    float s = 0.0f;
    for (int i = threadIdx.x; i < 4096; i += 256) s += partials[i];
    #pragma unroll
    for (int off = 32; off > 0; off >>= 1) s += __shfl_down(s, off);
    if ((threadIdx.x & 63) == 0) lds[threadIdx.x >> 6] = s;
    __syncthreads();
    if (threadIdx.x == 0) {
      const float total = lds[0] + lds[1] + lds[2] + lds[3];
      out_loss[0] = 0.25f * (total / 4194304.0f);
    }
    return;
  }
  __shared__ float4 red[4][64];
  const int k   = blockIdx.x;
  const int d4  = threadIdx.x & 63;
  const int rg  = threadIdx.x >> 6;
  const int s   = starts[k];
  const int e   = s + (int)counts[k];
  float4 acc = {0.f, 0.f, 0.f, 0.f};
  for (int i = s + rg; i < e; i += 4) {
    const float4 v = x4[bucket[i] * 64 + d4];
    acc.x += v.x; acc.y += v.y; acc.z += v.z; acc.w += v.w;
  }
  red[rg][d4] = acc;
  __syncthreads();
  if (rg == 0) {
    const float4 a1 = red[1][d4], a2 = red[2][d4], a3 = red[3][d4];
    acc.x += a1.x + a2.x + a3.x;
    acc.y += a1.y + a2.y + a3.y;
    acc.z += a1.z + a2.z + a3.z;
    acc.w += a1.w + a2.w + a3.w;
    const float csk = cs[k];
    const int g = k * DIM + d4 * 4;
    const float dwv[4] = {acc.x, acc.y, acc.z, acc.w};
    #pragma unroll
    for (int j = 0; j < 4; j++) {
      const float ev = ema_w[g + j] * 0.99f + 0.01f * dwv[j];
      out_ema_w[g + j] = ev;
      out_embed[g + j] = ev / csk;
    }
  }
}

// ------------------------------------------------------------------ launch ----
extern "C" void kernel_launch(void* const* d_in, const int* in_sizes, int n_in,
                              void* d_out, int out_size, void* d_ws, size_t ws_size,
                              hipStream_t stream) {
  const float* x       = (const float*)d_in[0];
  const float* embed_w = (const float*)d_in[1];
  const float* ema_cs  = (const float*)d_in[2];
  const float* ema_w   = (const float*)d_in[3];

  float* out        = (float*)d_out;
  float* out_q      = out;                 // 4194304
  float* out_loss   = out + 4194304;       // 1
  float* out_embed  = out + 4194305;       // 262144
  float* out_cs     = out + 4456449;       // 1024
  float* out_ema_w  = out + 4457473;       // 262144

  char* ws = (char*)d_ws;
  u64*   pairs    = (u64*)  (ws + 0);           // 2 MB [0, 2097152)
  int*   bucket   = (int*)  (ws + 0);           // 64 KB  (alias, post-merge)
  int*   idx      = (int*)  (ws + 2097152);     // 64 KB  [2097152, 2162688)
  float* counts   = (float*)(ws + 2162688);     // 4 KB
  int*   counter  = (int*)  (ws + 2166784);     // 4 B (adjacent to counts)
  int*   flags    = (int*)  (ws + 2166912);     // 32 KB
  float* wnorm    = (float*)(ws + 2199680);     // 4 KB
  float* cs_ws    = (float*)(ws + 2203776);     // 4 KB
  float* partials = (float*)(ws + 2207872);     // 16 KB
  int*   starts   = (int*)  (ws + 2224256);     // 4 KB
  int*   cursor   = (int*)  (ws + 2228352);     // 4 KB
  ushort* wh      = (ushort*)(ws + 2232448);    // 512 KB [2232448, 2756736)
  ushort* wl      = (ushort*)(ws + 2756736);    // 512 KB [2756736, 3281024)
  // ^ R8/R10 BUG: wl was at 2756608, overlapping wh's last 128 B (code 1023
  //   hi-plane clobbered by code 0 lo-plane) -> deterministic argmin flips.

  // x planes alias out_q (16 MB exactly; overwritten by quant_loss later).
  ushort* xh = (ushort*)out_q;                  // 8 MB
  ushort* xl = (ushort*)out_q + 4194304;        // 8 MB

  pack_wnorm_kernel<<<2180, 256, 0, stream>>>(
      (const float4*)x, (const float4*)embed_w, embed_w,
      (uint4*)xh, (uint4*)xl, (uint4*)wh, (uint4*)wl, wnorm, counts, counter);
  dist_mfma_kernel<<<(NROW / MT) * KSPLIT, 256, 0, stream>>>(xh, xl, wh, wl, wnorm, pairs);
  merge_kernel<<<NROW / 256, 256, 0, stream>>>(pairs, idx, counts, flags, counter);
  recheck_np_kernel<<<FCAP / RPB, 1024, 0, stream>>>(x, embed_w, wnorm, flags, counter,
                                                     idx, counts);
  prefix_cs_kernel<<<1, 1024, 0, stream>>>(ema_cs, counts, starts, cursor, out_cs, cs_ws);
  quant_loss_kernel<<<NROW * 64 / 256, 256, 0, stream>>>(
      (const float4*)x, (const float4*)embed_w, idx, (float4*)out_q, partials,
      cursor, bucket);
  dw_emb_kernel<<<KC + 1, 256, 0, stream>>>(
      (const float4*)x, bucket, starts, counts, ema_w, cs_ws, partials,
      out_ema_w, out_embed, out_loss);
}

// Round 12
// 182.547 us; speedup vs baseline: 3.6312x; 1.0145x over previous
//
#include <hip/hip_runtime.h>
#include <cstdint>
#include <cstddef>

// Problem constants (B=16, T=1024, D=256, K=1024)
namespace {
constexpr int NROW = 16384;   // B*T
constexpr int KC   = 1024;    // codes
constexpr int DIM  = 256;
constexpr int MT   = 128;     // rows per block (argmin GEMM)
constexpr int KSPLIT = 8;     // codes partitioned across blocks
constexpr int KPB  = KC / KSPLIT;   // 128 codes per block
constexpr int FCAP = 2048;    // flagged-row capacity (expect ~450; R19: was 8192)
constexpr int RPB  = 4;       // flagged rows per recheck block
}

typedef __attribute__((ext_vector_type(8))) short bf16x8;
typedef __attribute__((ext_vector_type(4))) float f32x4;
typedef unsigned long long u64;
typedef uint32_t u32;

// Monotone float -> uint key (ascending), for packed argmin with index tie-break.
__device__ __forceinline__ unsigned fkey(float s) {
  unsigned u = __float_as_uint(s);
  return ((int)u >= 0) ? (u ^ 0x80000000u) : ~u;
}
__device__ __forceinline__ float unfkey(unsigned u) {
  return __uint_as_float((u & 0x80000000u) ? (u ^ 0x80000000u) : ~u);
}

// Split fp32 a into RNE-bf16 hi + RNE-bf16 of exact residual (low 16 bits each).
__device__ __forceinline__ void split2(float a, u32& h, u32& l) {
  const u32 u  = __float_as_uint(a);
  const u32 rh = (u + 0x7fffu + ((u >> 16) & 1u)) >> 16;
  const float ah = __uint_as_float(rh << 16);
  const float al = a - ah;                      // exact (Sterbenz)
  const u32 v  = __float_as_uint(al);
  const u32 rl = (v + 0x7fffu + ((v >> 16) & 1u)) >> 16;
  h = rh & 0xffffu; l = rl & 0xffffu;
}

// numpy pairwise sum of squares of 256 floats, bit-exact emulation.
__device__ __forceinline__ float np_sumsq_256(const float* __restrict__ p) {
  float half[2];
  #pragma unroll
  for (int h = 0; h < 2; h++) {
    const float* q = p + h * 128;
    float r[8];
    #pragma unroll
    for (int j = 0; j < 8; j++) r[j] = __fmul_rn(q[j], q[j]);
    #pragma unroll 1
    for (int i = 8; i < 128; i += 8)
      #pragma unroll
      for (int j = 0; j < 8; j++)
        r[j] = __fadd_rn(r[j], __fmul_rn(q[i + j], q[i + j]));
    half[h] = __fadd_rn(__fadd_rn(__fadd_rn(r[0], r[1]), __fadd_rn(r[2], r[3])),
                        __fadd_rn(__fadd_rn(r[4], r[5]), __fadd_rn(r[6], r[7])));
  }
  return __fadd_rn(half[0], half[1]);
}

// ------------------------------------------------- pack planes + wnorm ----
// R17: wnorm branch (1024 threads) also zeroes counts+counter — replaces the
// hipMemsetAsync dispatch. pack runs before merge on the stream, so ordering
// is identical to the old memset.
__global__ __launch_bounds__(256)
void pack_wnorm_kernel(const float4* __restrict__ x4, const float4* __restrict__ w4,
                       const float* __restrict__ w,
                       uint4* __restrict__ xh4, uint4* __restrict__ xl4,
                       uint4* __restrict__ wh4, uint4* __restrict__ wl4,
                       float* __restrict__ wnorm,
                       float* __restrict__ counts, int* __restrict__ counter) {
  if (blockIdx.x >= 2176) {
    const int k = (blockIdx.x - 2176) * 256 + threadIdx.x;
    counts[k] = 0.0f;
    if (k == 0) counter[0] = 0;
    wnorm[k] = np_sumsq_256(&w[k * DIM]);
    return;
  }
  const int g = blockIdx.x * 256 + threadIdx.x;
  const float4* src; uint4* dh; uint4* dl; int gg;
  if (g < 524288) { gg = g;          src = x4; dh = xh4; dl = xl4; }
  else            { gg = g - 524288; src = w4; dh = wh4; dl = wl4; }
  const float4 a = src[gg * 2], b = src[gg * 2 + 1];
  u32 h[8], l[8];
  split2(a.x, h[0], l[0]); split2(a.y, h[1], l[1]);
  split2(a.z, h[2], l[2]); split2(a.w, h[3], l[3]);
  split2(b.x, h[4], l[4]); split2(b.y, h[5], l[5]);
  split2(b.z, h[6], l[6]); split2(b.w, h[7], l[7]);
  uint4 H, L;
  H.x = h[0] | (h[1] << 16); H.y = h[2] | (h[3] << 16);
  H.z = h[4] | (h[5] << 16); H.w = h[6] | (h[7] << 16);
  L.x = l[0] | (l[1] << 16); L.y = l[2] | (l[3] << 16);
  L.z = l[4] | (l[5] << 16); L.w = l[6] | (l[7] << 16);
  dh[gg] = H; dl[gg] = L;
}

// ------------------------------------------- split-bf16 MFMA dist + top-2 ----
// KSPLIT=8: block = 128 rows x 128 codes, 32 KB LDS. Lane-contiguous
// global_load_lds staging; XCD swizzle (8 ksplit siblings share bid%8).
// R12: XOR bank swizzle (rule #21: pre-swizzled global source + swizzled
// ds_read, LDS dest linear) + 4 blocks/CU. R13 (dbuf), R14 (counted vmcnt)
// null; R15 (atomic dw), R16 (device-fence fusion) regressed — reverted.
__global__ __launch_bounds__(256, 4)
void dist_mfma_kernel(const ushort* __restrict__ xh, const ushort* __restrict__ xl,
                      const ushort* __restrict__ wh, const ushort* __restrict__ wl,
                      const float* __restrict__ wnorm,
                      u64* __restrict__ pairs) {
  __shared__ __align__(16) u32 lds[8192];   // 32 KB: AH 8K | AL 8K | BH 8K | BL 8K

  const int tid  = threadIdx.x;
  const int lane = tid & 63;
  const int wv   = tid >> 6;
  const int quad = lane >> 4;
  const int idx16 = lane & 15;
  const int bid  = blockIdx.x;
  const int rowBase = (((bid >> 6) << 3) | (bid & 7)) * MT;
  const int sp      = (bid >> 3) & 7;
  const int kbase   = sp * KPB;

  // 32 staging chunks of 1 KB (16 rows x 64 B); wave wv handles 8.
  // Source slot is pre-swizzled: LDS(row, s) holds global(row, s ^ ((row>>1)&3)).
  const int subrow = lane >> 2, grp = lane & 3;
  const int sgrp = grp ^ ((subrow >> 1) & 3);
  const ushort* gptr[8];
  u32 ldst[8];
  #pragma unroll
  for (int j = 0; j < 8; j++) {
    const int c = wv * 8 + j;
    const ushort* plane; int r0; u32 dstB;
    if (c < 8)       { plane = xh + rowBase * DIM; r0 = c * 16;        dstB = c * 1024; }
    else if (c < 16) { plane = xl + rowBase * DIM; r0 = (c - 8) * 16;  dstB = 8192 + (c - 8) * 1024; }
    else if (c < 24) { plane = wh + kbase * DIM;   r0 = (c - 16) * 16; dstB = 16384 + (c - 16) * 1024; }
    else             { plane = wl + kbase * DIM;   r0 = (c - 24) * 16; dstB = 24576 + (c - 24) * 1024; }
    gptr[j] = plane + (r0 + subrow) * DIM + sgrp * 8;
    ldst[j] = dstB >> 2;
  }

  f32x4 acc[2][8];
  #pragma unroll
  for (int rt = 0; rt < 2; rt++)
    #pragma unroll
    for (int ct = 0; ct < 8; ct++) acc[rt][ct] = (f32x4){0.f, 0.f, 0.f, 0.f};

  // Read-side swizzle: both ar and br are ≡ idx16 (mod 16), so the XOR term
  // is uniform per lane across all A/B fragment reads.
  const int slotOff = (quad ^ ((idx16 >> 1) & 3)) * 16;

  #pragma unroll 1
  for (int kc = 0; kc < DIM / 32; kc++) {
    __syncthreads();   // previous readers done
    #pragma unroll
    for (int j = 0; j < 8; j++) {
      __builtin_amdgcn_global_load_lds(
          (const __attribute__((address_space(1))) u32*)(gptr[j]),
          (__attribute__((address_space(3))) u32*)&lds[ldst[j]], 16, 0, 0);
      gptr[j] += 32;   // next 32 K-elems
    }
    __syncthreads();   // drains vmcnt; LDS visible

    bf16x8 Ah[2], Al[2];
    #pragma unroll
    for (int rt = 0; rt < 2; rt++) {
      const int ar = wv * 32 + rt * 16 + idx16;
      Ah[rt] = *(const bf16x8*)((const char*)lds + ar * 64 + slotOff);
      Al[rt] = *(const bf16x8*)((const char*)lds + 8192 + ar * 64 + slotOff);
    }
    #pragma unroll
    for (int ct = 0; ct < 8; ct++) {
      const int br = ct * 16 + idx16;
      const bf16x8 Bh = *(const bf16x8*)((const char*)lds + 16384 + br * 64 + slotOff);
      const bf16x8 Bl = *(const bf16x8*)((const char*)lds + 24576 + br * 64 + slotOff);
      #pragma unroll
      for (int rt = 0; rt < 2; rt++) {
        acc[rt][ct] = __builtin_amdgcn_mfma_f32_16x16x32_bf16(Al[rt], Bh, acc[rt][ct], 0, 0, 0);
        acc[rt][ct] = __builtin_amdgcn_mfma_f32_16x16x32_bf16(Ah[rt], Bl, acc[rt][ct], 0, 0, 0);
        acc[rt][ct] = __builtin_amdgcn_mfma_f32_16x16x32_bf16(Ah[rt], Bh, acc[rt][ct], 0, 0, 0);
      }
    }
  }

  // Epilogue: score = wnorm - 2*dot; per-lane top-2, then 4-stage butterfly.
  u64 b0[2][4], b1[2][4];
  #pragma unroll
  for (int rt = 0; rt < 2; rt++)
    #pragma unroll
    for (int reg = 0; reg < 4; reg++) { b0[rt][reg] = ~0ULL; b1[rt][reg] = ~0ULL; }

  #pragma unroll
  for (int ct = 0; ct < 8; ct++) {
    const int col = kbase + ct * 16 + idx16;
    const float wn = wnorm[col];
    #pragma unroll
    for (int rt = 0; rt < 2; rt++) {
      #pragma unroll
      for (int reg = 0; reg < 4; reg++) {
        const float s = fmaf(-2.0f, acc[rt][ct][reg], wn);
        const u64 p = ((u64)fkey(s) << 32) | (unsigned)col;
        if (p < b1[rt][reg]) {
          if (p < b0[rt][reg]) { b1[rt][reg] = b0[rt][reg]; b0[rt][reg] = p; }
          else                 { b1[rt][reg] = p; }
        }
      }
    }
  }

  #pragma unroll
  for (int m = 1; m <= 8; m <<= 1) {
    #pragma unroll
    for (int rt = 0; rt < 2; rt++) {
      #pragma unroll
      for (int reg = 0; reg < 4; reg++) {
        const u64 o0 = __shfl_xor(b0[rt][reg], m);
        const u64 o1 = __shfl_xor(b1[rt][reg], m);
        if (o0 < b0[rt][reg]) {
          b1[rt][reg] = (b0[rt][reg] < o1) ? b0[rt][reg] : o1;
          b0[rt][reg] = o0;
        } else {
          b1[rt][reg] = (b1[rt][reg] < o0) ? b1[rt][reg] : o0;
        }
      }
    }
  }

  if (idx16 == 0) {
    #pragma unroll
    for (int rt = 0; rt < 2; rt++) {
      #pragma unroll
      for (int reg = 0; reg < 4; reg++) {
        const int row = rowBase + wv * 32 + rt * 16 + quad * 4 + reg;
        pairs[row * 16 + sp * 2 + 0] = b0[rt][reg];
        pairs[row * 16 + sp * 2 + 1] = b1[rt][reg];
      }
    }
  }
}

// ------------------------------------- merge splits + flag + counts ----
__global__ __launch_bounds__(256)
void merge_kernel(const u64* __restrict__ pairs,
                  int* __restrict__ idx, float* __restrict__ counts,
                  int* __restrict__ flags, int* __restrict__ counter) {
  const int row = blockIdx.x * 256 + threadIdx.x;
  const u64* p = &pairs[row * 16];
  u64 B0 = p[0], B1 = p[1];
  #pragma unroll
  for (int s = 1; s < KSPLIT; s++) {
    const u64 c0 = p[s * 2], c1 = p[s * 2 + 1];
    if (c0 < B0) { B1 = (B0 < c1) ? B0 : c1; B0 = c0; }
    else         { B1 = (B1 < c0) ? B1 : c0; }
  }
  const int k = (int)(B0 & 0xffffffffULL);
  idx[row] = k;
  atomicAdd(&counts[k], 1.0f);
  const float s0 = unfkey((unsigned)(B0 >> 32));
  const float s1 = unfkey((unsigned)(B1 >> 32));
  if (s1 - s0 < 2e-4f) {
    const int pos = atomicAdd(counter, 1);
    if (pos < FCAP) flags[pos] = row;
  }
}

// --------------------- np-fp32-emulating recheck; adjusts counts on flips ----
// R11 structure: 1024 threads/block, one code per thread; x rows
// pre-converted to double in LDS once; u64 argmin via wave shfl_xor reduce.
// FMA order per (row,code) unchanged -> bit-identical results.
// R19: FCAP 8192->2048 (grid 512 blocks; ~450 flagged rows measured stable
// across 11 rounds on this fixed-seed input — 4.5x margin).
// NOTE (R16 lesson): __threadfence() on gfx950 = per-XCD L2 writeback
// broadcasts; in a wide grid it cost ~510 us. Never wide device fences.
__global__ __launch_bounds__(1024)
void recheck_np_kernel(const float* __restrict__ x, const float* __restrict__ w,
                       const float* __restrict__ wnorm,
                       const int* __restrict__ flags, const int* __restrict__ counter,
                       int* __restrict__ idx, float* __restrict__ counts) {
  __shared__ float  xs[RPB][DIM];    // 4 KB
  __shared__ double xd[RPB][DIM];    // 8 KB
  __shared__ float  x2sh[RPB];
  __shared__ u64    red[RPB][16];

  const int cnt  = min(*counter, FCAP);
  const int base = blockIdx.x * RPB;
  if (base >= cnt) return;
  const int nr = min(RPB, cnt - base);

  {
    const int r = threadIdx.x >> 8, d = threadIdx.x & 255;
    const float v = (r < nr) ? x[flags[base + r] * DIM + d] : 0.0f;
    xs[r][d] = v;
    xd[r][d] = (double)v;
  }
  __syncthreads();
  if (threadIdx.x < RPB) x2sh[threadIdx.x] = np_sumsq_256(xs[threadIdx.x]);
  __syncthreads();

  double x2d[RPB];
  #pragma unroll
  for (int r = 0; r < RPB; r++) x2d[r] = (double)x2sh[r];

  const int k = threadIdx.x;                    // one code per thread
  const float* __restrict__ wr = &w[k * DIM];
  const double w2 = (double)wnorm[k];

  double dot[RPB];
  #pragma unroll
  for (int r = 0; r < RPB; r++) dot[r] = 0.0;

  float4 wv[4];
  #pragma unroll
  for (int q = 0; q < 4; q++) wv[q] = *(const float4*)&wr[q * 4];

  #pragma unroll 1
  for (int d = 0; d < DIM; d += 16) {
    float4 cur[4];
    #pragma unroll
    for (int q = 0; q < 4; q++) cur[q] = wv[q];
    if (d + 16 < DIM) {
      #pragma unroll
      for (int q = 0; q < 4; q++) wv[q] = *(const float4*)&wr[d + 16 + q * 4];
    }
    #pragma unroll
    for (int q = 0; q < 4; q++) {
      const double wa = (double)cur[q].x, wb = (double)cur[q].y,
                   wc = (double)cur[q].z, wd_ = (double)cur[q].w;
      #pragma unroll
      for (int r = 0; r < RPB; r++) {
        dot[r] = fma(xd[r][d + q * 4 + 0], wa,  dot[r]);
        dot[r] = fma(xd[r][d + q * 4 + 1], wb,  dot[r]);
        dot[r] = fma(xd[r][d + q * 4 + 2], wc,  dot[r]);
        dot[r] = fma(xd[r][d + q * 4 + 3], wd_, dot[r]);
      }
    }
  }

  u64 key[RPB];
  #pragma unroll
  for (int r = 0; r < RPB; r++) {
    const float mmf = (float)dot[r];
    const float S1  = (float)(x2d[r] + w2);
    const float D   = (float)((double)S1 - 2.0 * (double)mmf);
    key[r] = ((u64)fkey(D) << 32) | (unsigned)k;
  }

  // wave-level u64 min (6 butterfly stages)
  #pragma unroll
  for (int m = 1; m < 64; m <<= 1) {
    #pragma unroll
    for (int r = 0; r < RPB; r++) {
      const u64 o = __shfl_xor(key[r], m);
      if (o < key[r]) key[r] = o;
    }
  }
  if ((threadIdx.x & 63) == 0) {
    const int wid = threadIdx.x >> 6;
    #pragma unroll
    for (int r = 0; r < RPB; r++) red[r][wid] = key[r];
  }
  __syncthreads();
  if (threadIdx.x < 64) {                       // wave 0: 16 lanes per row
    const int r = threadIdx.x >> 4, l = threadIdx.x & 15;
    u64 kk = red[r][l];
    #pragma unroll
    for (int m = 1; m < 16; m <<= 1) {
      const u64 o = __shfl_xor(kk, m);
      if (o < kk) kk = o;
    }
    if (l == 0 && r < nr) {
      const int row  = flags[base + r];
      const int newk = (int)(kk & 0xffffffffULL);
      const int oldk = idx[row];
      if (newk != oldk) {
        idx[row] = newk;
        atomicAdd(&counts[newk],  1.0f);
        atomicAdd(&counts[oldk], -1.0f);
      }
    }
  }
}

// ------------------------------- fused prefix scan (starts/cursor) + cs ----
// R19: 1024-wide Hillis-Steele (10 rounds x 2 barriers = 20 barriers)
// replaced by 3-level scan: shfl_up inclusive scan within each 64-lane wave
// (no barriers), 16 wave totals via LDS (1 barrier), serial carry-in of
// <=15 wave totals per thread (LDS broadcasts). Same int arithmetic ->
// identical starts/cursor values.
__global__ __launch_bounds__(1024)
void prefix_cs_kernel(const float* __restrict__ ema_cs, const float* __restrict__ counts,
                      int* __restrict__ starts, int* __restrict__ cursor,
                      float* __restrict__ out_cs, float* __restrict__ cs_ws) {
  __shared__ int   wsum[16];
  __shared__ float lds[17];
  const int t    = threadIdx.x;
  const int lane = t & 63;
  const int wid  = t >> 6;

  const int ci = (int)counts[t];

  // wave-inclusive scan (int)
  int v = ci;
  #pragma unroll
  for (int off = 1; off < 64; off <<= 1) {
    const int o = __shfl_up(v, off);
    if (lane >= off) v += o;
  }
  if (lane == 63) wsum[wid] = v;

  // cs sum (float) reuses the same barrier
  const float c = ema_cs[t] * 0.99f + 0.01f * counts[t];
  float fv = c;
  #pragma unroll
  for (int off = 32; off > 0; off >>= 1) fv += __shfl_down(fv, off);
  if (lane == 0) lds[wid] = fv;
  __syncthreads();

  if (t == 0) {
    float n = 0.0f;
    for (int i = 0; i < 16; i++) n += lds[i];
    lds[16] = n;
  }
  int carry = 0;
  for (int wx = 0; wx < wid; wx++) carry += wsum[wx];
  __syncthreads();

  const float n = lds[16];
  const float csv = (c + 1e-5f) / (n + 1024.0f * 1e-5f) * n;
  out_cs[t] = csv;
  cs_ws[t]  = csv;

  const int excl = carry + v - ci;   // exclusive prefix
  starts[t] = excl;
  cursor[t] = excl;
}

// -------------- quantize + loss + bucket scatter (R17 fusion, no fences) ----
// The d4==0 lane of each row (one per row, 16384 total — same atomic count
// as the old scatter_kernel) appends its row to the cluster bucket. Bucket
// order within a cluster changes vs the old scatter, but it was already
// nondeterministic (atomic cursor); only permutes dw summation order.
__global__ __launch_bounds__(256)
void quant_loss_kernel(const float4* __restrict__ x4,
                       const float4* __restrict__ w4,
                       const int* __restrict__ idx,
                       float4* __restrict__ outq,
                       float* __restrict__ partials,
                       int* __restrict__ cursor, int* __restrict__ bucket) {
  __shared__ float lds[4];
  const int g  = blockIdx.x * 256 + threadIdx.x;
  const int n  = g >> 6;
  const int d4 = g & 63;
  const float4 xv = x4[g];
  const int   k  = idx[n];
  if (d4 == 0) {
    const int pos = atomicAdd(&cursor[k], 1);
    bucket[pos] = n;
  }
  const float4 qv = w4[k * 64 + d4];
  float4 r;
  r.x = xv.x + (qv.x - xv.x);
  r.y = xv.y + (qv.y - xv.y);
  r.z = xv.z + (qv.z - xv.z);
  r.w = xv.w + (qv.w - xv.w);
  outq[g] = r;

  const float dx = xv.x - r.x, dy = xv.y - r.y, dz = xv.z - r.z, dwv = xv.w - r.w;
  float s = dx * dx + dy * dy + dz * dz + dwv * dwv;
  #pragma unroll
  for (int off = 32; off > 0; off >>= 1) s += __shfl_down(s, off);
  if ((threadIdx.x & 63) == 0) lds[threadIdx.x >> 6] = s;
  __syncthreads();
  if (threadIdx.x == 0) partials[blockIdx.x] = lds[0] + lds[1] + lds[2] + lds[3];
}

// ------- per-cluster dw reduction + fused ema_w/embed + loss (R18) ----
// Block k holds dw[k]'s 256 values in registers after the LDS reduction —
// apply ema_w*0.99+0.01*dw and /cs[k] directly; dw never touches memory.
// Loss finalize in extra block KC. Math bit-identical to former emb_loss.
__global__ __launch_bounds__(256)
void dw_emb_kernel(const float4* __restrict__ x4, const int* __restrict__ bucket,
                   const int* __restrict__ starts, const float* __restrict__ counts,
                   const float* __restrict__ ema_w, const float* __restrict__ cs,
                   const float* __restrict__ partials,
                   float* __restrict__ out_ema_w, float* __restrict__ out_embed,
                   float* __restrict__ out_loss) {
  if (blockIdx.x == KC) {   // loss finalize
    __shared__ float lds[4];
    float s = 0.0f;
    for (int i = threadIdx.x; i < 4096; i += 256) s += partials[i];
    #pragma unroll
    for (int off = 32; off > 0; off >>= 1) s += __shfl_down(s, off);
    if ((threadIdx.x & 63) == 0) lds[threadIdx.x >> 6] = s;
    __syncthreads();
    if (threadIdx.x == 0) {
      const float total = lds[0] + lds[1] + lds[2] + lds[3];
      out_loss[0] = 0.25f * (total / 4194304.0f);
    }
    return;
  }
  __shared__ float4 red[4][64];
  const int k   = blockIdx.x;
  const int d4  = threadIdx.x & 63;
  const int rg  = threadIdx.x >> 6;
  const int s   = starts[k];
  const int e   = s + (int)counts[k];
  float4 acc = {0.f, 0.f, 0.f, 0.f};
  for (int i = s + rg; i < e; i += 4) {
    const float4 v = x4[bucket[i] * 64 + d4];
    acc.x += v.x; acc.y += v.y; acc.z += v.z; acc.w += v.w;
  }
  red[rg][d4] = acc;
  __syncthreads();
  if (rg == 0) {
    const float4 a1 = red[1][d4], a2 = red[2][d4], a3 = red[3][d4];
    acc.x += a1.x + a2.x + a3.x;
    acc.y += a1.y + a2.y + a3.y;
    acc.z += a1.z + a2.z + a3.z;
    acc.w += a1.w + a2.w + a3.w;
    const float csk = cs[k];
    const int g = k * DIM + d4 * 4;
    const float dwv[4] = {acc.x, acc.y, acc.z, acc.w};
    #pragma unroll
    for (int j = 0; j < 4; j++) {
      const float ev = ema_w[g + j] * 0.99f + 0.01f * dwv[j];
      out_ema_w[g + j] = ev;
      out_embed[g + j] = ev / csk;
    }
  }
}

// ------------------------------------------------------------------ launch ----
extern "C" void kernel_launch(void* const* d_in, const int* in_sizes, int n_in,
                              void* d_out, int out_size, void* d_ws, size_t ws_size,
                              hipStream_t stream) {
  const float* x       = (const float*)d_in[0];
  const float* embed_w = (const float*)d_in[1];
  const float* ema_cs  = (const float*)d_in[2];
  const float* ema_w   = (const float*)d_in[3];

  float* out        = (float*)d_out;
  float* out_q      = out;                 // 4194304
  float* out_loss   = out + 4194304;       // 1
  float* out_embed  = out + 4194305;       // 262144
  float* out_cs     = out + 4456449;       // 1024
  float* out_ema_w  = out + 4457473;       // 262144

  char* ws = (char*)d_ws;
  u64*   pairs    = (u64*)  (ws + 0);           // 2 MB [0, 2097152)
  int*   bucket   = (int*)  (ws + 0);           // 64 KB  (alias, post-merge)
  int*   idx      = (int*)  (ws + 2097152);     // 64 KB  [2097152, 2162688)
  float* counts   = (float*)(ws + 2162688);     // 4 KB
  int*   counter  = (int*)  (ws + 2166784);     // 4 B (adjacent to counts)
  int*   flags    = (int*)  (ws + 2166912);     // 32 KB (FCAP=2048 uses 8 KB)
  float* wnorm    = (float*)(ws + 2199680);     // 4 KB
  float* cs_ws    = (float*)(ws + 2203776);     // 4 KB
  float* partials = (float*)(ws + 2207872);     // 16 KB
  int*   starts   = (int*)  (ws + 2224256);     // 4 KB
  int*   cursor   = (int*)  (ws + 2228352);     // 4 KB
  ushort* wh      = (ushort*)(ws + 2232448);    // 512 KB [2232448, 2756736)
  ushort* wl      = (ushort*)(ws + 2756736);    // 512 KB [2756736, 3281024)
  // ^ R8/R10 BUG: wl was at 2756608, overlapping wh's last 128 B (code 1023
  //   hi-plane clobbered by code 0 lo-plane) -> deterministic argmin flips.

  // x planes alias out_q (16 MB exactly; overwritten by quant_loss later).
  ushort* xh = (ushort*)out_q;                  // 8 MB
  ushort* xl = (ushort*)out_q + 4194304;        // 8 MB

  pack_wnorm_kernel<<<2180, 256, 0, stream>>>(
      (const float4*)x, (const float4*)embed_w, embed_w,
      (uint4*)xh, (uint4*)xl, (uint4*)wh, (uint4*)wl, wnorm, counts, counter);
  dist_mfma_kernel<<<(NROW / MT) * KSPLIT, 256, 0, stream>>>(xh, xl, wh, wl, wnorm, pairs);
  merge_kernel<<<NROW / 256, 256, 0, stream>>>(pairs, idx, counts, flags, counter);
  recheck_np_kernel<<<FCAP / RPB, 1024, 0, stream>>>(x, embed_w, wnorm, flags, counter,
                                                     idx, counts);
  prefix_cs_kernel<<<1, 1024, 0, stream>>>(ema_cs, counts, starts, cursor, out_cs, cs_ws);
  quant_loss_kernel<<<NROW * 64 / 256, 256, 0, stream>>>(
      (const float4*)x, (const float4*)embed_w, idx, (float4*)out_q, partials,
      cursor, bucket);
  dw_emb_kernel<<<KC + 1, 256, 0, stream>>>(
      (const float4*)x, bucket, starts, counts, ema_w, cs_ws, partials,
      out_ema_w, out_embed, out_loss);
}